// Round 6
// baseline (103.898 us; speedup 1.0000x reference)
//
#include <hip/hip_runtime.h>
#include <hip/hip_bf16.h>
#include <stdint.h>

// Problem constants
#define NF 4096
#define NS 1024
#define MD 512
#define HD 64
#define DA 96
#define GHID 128

#define L2E 1.44269504f          // log2(e)
#define S2L 1.6986436f           // sqrt(2*log2e)  (LAMBDA_GEO=1)

typedef unsigned short u16;
typedef __attribute__((ext_vector_type(8))) short bf8v;   // 8 bf16
typedef __attribute__((ext_vector_type(4))) float f4v;

__device__ __forceinline__ u16 f2bf(float f) {
  __hip_bfloat16 h = __float2bfloat16(f);
  return __builtin_bit_cast(u16, h);
}
__device__ __forceinline__ float bf2f(u16 u) {
  union { unsigned u; float f; } v; v.u = ((unsigned)u) << 16; return v.f;
}
__device__ __forceinline__ f4v mfma16(bf8v a, bf8v b, f4v c) {
  return __builtin_amdgcn_mfma_f32_16x16x32_bf16(a, b, c, 0, 0, 0);
}
__device__ __forceinline__ void gld16(const void* g, void* l) {
  __builtin_amdgcn_global_load_lds(
      (const __attribute__((address_space(1))) unsigned int*)g,
      (__attribute__((address_space(3))) unsigned int*)l, 16, 0, 0);
}

// weight pool offsets (bf16 elements)
#define OFF_POSW2 0
#define OFF_FAW   262144
#define OFF_SAW   425984
#define OFF_WQ    819200
#define OFF_WKV   1081344
#define OFF_PLKW2 1605632
#define OFF_SXYW2 1622016
#define OFF_WQG   1638400
#define OFF_WKG   1654784
#define OFF_SATT  1671168
#define TOTW      2457600

// ================= L0: convert weights + ffT transpose + 3 silu MLPs =================
// blocks: [0,2401) convert, [2401,3041) ffT, [3041,13793) silu
__global__ __launch_bounds__(256) void k_l0(
    const float* __restrict__ s0, const float* __restrict__ s1,
    const float* __restrict__ s2, const float* __restrict__ s3,
    const float* __restrict__ s4, const float* __restrict__ s5,
    const float* __restrict__ s6, const float* __restrict__ s7,
    const float* __restrict__ s8, const float* __restrict__ s9,
    const float* __restrict__ s10, u16* __restrict__ pool,
    const float* __restrict__ bk, const float* __restrict__ bv,
    float* __restrict__ bkv,
    const float* __restrict__ ff, u16* __restrict__ ffT,
    const float* __restrict__ in0, const float* __restrict__ w0,
    const float* __restrict__ b0, u16* __restrict__ o0,
    const float* __restrict__ in1, const float* __restrict__ w1,
    const float* __restrict__ b1, u16* __restrict__ o1,
    const float* __restrict__ in2, const float* __restrict__ w2,
    const float* __restrict__ b2, u16* __restrict__ o2) {
  __shared__ u16 sT[32][72];
  int blk = blockIdx.x, t = threadIdx.x;
  if (blk < 2401) {
    int i4 = blk * 256 + t;
    if (i4 < TOTW / 4) {
      int idx = i4 * 4;
      const float* src; int off;
      if      (idx < OFF_FAW)   { src = s0;  off = OFF_POSW2; }
      else if (idx < OFF_SAW)   { src = s1;  off = OFF_FAW; }
      else if (idx < OFF_WQ)    { src = s2;  off = OFF_SAW; }
      else if (idx < OFF_WKV)   { src = s3;  off = OFF_WQ; }
      else if (idx < 1343488)   { src = s4;  off = OFF_WKV; }
      else if (idx < OFF_PLKW2) { src = s5;  off = 1343488; }
      else if (idx < OFF_SXYW2) { src = s6;  off = OFF_PLKW2; }
      else if (idx < OFF_WQG)   { src = s7;  off = OFF_SXYW2; }
      else if (idx < OFF_WKG)   { src = s8;  off = OFF_WQG; }
      else if (idx < OFF_SATT)  { src = s9;  off = OFF_WKG; }
      else                      { src = s10; off = OFF_SATT; }
      float4 v = *(const float4*)(src + (idx - off));
      ushort4 o;
      o.x = f2bf(v.x); o.y = f2bf(v.y); o.z = f2bf(v.z); o.w = f2bf(v.w);
      *(ushort4*)(pool + idx) = o;
    } else if (i4 < TOTW / 4 + 256) {
      int j = (i4 - TOTW / 4) * 4;
#pragma unroll
      for (int e = 0; e < 4; ++e) {
        int b = j + e;
        bkv[b] = (b < 512) ? bk[b] : bv[b - 512];
      }
    }
  } else if (blk < 3041) {
    int lb = blk - 2401;
    int n0 = (lb & 63) * 64, c0 = (lb >> 6) * 32;
    {
      int cr = t >> 3, nc = (t & 7) * 8;
      const float* src = ff + (size_t)(c0 + cr) * NF + n0 + nc;
      float4 v0 = *(const float4*)src, v1 = *(const float4*)(src + 4);
      bf8v p;
      p[0]=(short)f2bf(v0.x); p[1]=(short)f2bf(v0.y); p[2]=(short)f2bf(v0.z); p[3]=(short)f2bf(v0.w);
      p[4]=(short)f2bf(v1.x); p[5]=(short)f2bf(v1.y); p[6]=(short)f2bf(v1.z); p[7]=(short)f2bf(v1.w);
      *(bf8v*)&sT[cr][nc] = p;
    }
    __syncthreads();
    {
      int r = t >> 2, cc = (t & 3) * 8;
      bf8v p;
#pragma unroll
      for (int e = 0; e < 8; ++e) p[e] = (short)sT[cc + e][r];
      *(bf8v*)(ffT + (size_t)(n0 + r) * 320 + c0 + cc) = p;
    }
  } else {
    int lb = blk - 3041;
    const float *in, *w, *b; u16* o; int mlog, K, idx;
    if (lb < 8192)       { in = in0; w = w0; b = b0; o = o0; mlog = 9; K = 2; idx = lb * 256 + t; }
    else if (lb < 10240) { in = in1; w = w1; b = b1; o = o1; mlog = 7; K = 6; idx = (lb - 8192) * 256 + t; }
    else                 { in = in2; w = w2; b = b2; o = o2; mlog = 7; K = 2; idx = (lb - 10240) * 256 + t; }
    int M = 1 << mlog;
    int n = idx >> mlog, m = idx & (M - 1);
    float acc = b[m];
    for (int k = 0; k < K; ++k) acc += in[n * K + k] * w[m * K + k];
    o[idx] = f2bf(acc / (1.f + __expf(-acc)));
  }
}

// ================= bf16 MFMA GEMM body, 128x128 tile, BK=32, dbuf LDS =================
// swizzle: 16B chunk index ^= (row ^ row>>2) & 3  (both-sides involution, 2-way banks)
__device__ __forceinline__ void gemm_body(const u16* __restrict__ A, const u16* __restrict__ W,
                                          const float* __restrict__ bias, u16* __restrict__ out,
                                          int m0, int n0, int N, int K) {
  __shared__ u16 sA[2][128 * 32];
  __shared__ u16 sB[2][128 * 32];
  const int tid = threadIdx.x, w = tid >> 6, lane = tid & 63;
  const int l16 = lane & 15, lh = lane >> 4;
  const int wr = w >> 1, wc = w & 1;

  f4v acc[4][4];
#pragma unroll
  for (int m = 0; m < 4; ++m)
#pragma unroll
    for (int j = 0; j < 4; ++j) acc[m][j] = (f4v){0.f, 0.f, 0.f, 0.f};

  auto stage = [&](const u16* __restrict__ src, u16* dst, int r0, int k0, int K_) {
#pragma unroll
    for (int i = 0; i < 2; ++i) {
      int c = i * 256 + tid;
      int row = c >> 2, s = c & 3;
      int g = s ^ ((row ^ (row >> 2)) & 3);
      gld16(src + (size_t)(r0 + row) * K_ + k0 + g * 8, dst + c * 8);
    }
  };

  stage(A, sA[0], m0, 0, K);
  stage(W, sB[0], n0, 0, K);
  __syncthreads();
  const int NK = K >> 5;
  for (int ks = 0; ks < NK; ++ks) {
    int nb = ks & 1;
    if (ks + 1 < NK) {
      stage(A, sA[nb ^ 1], m0, (ks + 1) * 32, K);
      stage(W, sB[nb ^ 1], n0, (ks + 1) * 32, K);
    }
    bf8v af[4], bfr[4];
#pragma unroll
    for (int m = 0; m < 4; ++m) {
      int row = wr * 64 + m * 16 + l16;
      int s = lh ^ ((row ^ (row >> 2)) & 3);
      af[m] = *(const bf8v*)&sA[nb][row * 32 + s * 8];
    }
#pragma unroll
    for (int j = 0; j < 4; ++j) {
      int row = wc * 64 + j * 16 + l16;
      int s = lh ^ ((row ^ (row >> 2)) & 3);
      bfr[j] = *(const bf8v*)&sB[nb][row * 32 + s * 8];
    }
#pragma unroll
    for (int m = 0; m < 4; ++m)
#pragma unroll
      for (int j = 0; j < 4; ++j) acc[m][j] = mfma16(af[m], bfr[j], acc[m][j]);
    __syncthreads();
  }
#pragma unroll
  for (int m = 0; m < 4; ++m) {
    int grow = m0 + wr * 64 + m * 16 + (lh << 2);
#pragma unroll
    for (int j = 0; j < 4; ++j) {
      int gcol = n0 + wc * 64 + j * 16 + l16;
      float bv = bias ? bias[gcol] : 0.f;
#pragma unroll
      for (int r = 0; r < 4; ++r)
        out[(size_t)(grow + r) * N + gcol] = f2bf(acc[m][j][r] + bv);
    }
  }
}

struct GP { const u16* A; const u16* W; const float* bias; u16* out; int K; int N; int M; };

__device__ __forceinline__ void gemm_dispatch(const GP& g, int blk) {
  int mt = g.M >> 7;
  int m0 = (blk % mt) * 128, n0 = (blk / mt) * 128;
  gemm_body(g.A, g.W, g.bias, g.out, m0, n0, g.N, g.K);
}

// L1 (longest K first): sat(32) pos(128) feat(128) geo1q(32) geo1k(8) = 328 blocks
__global__ __launch_bounds__(256) void k_gemm_L1(GP sat, GP pos, GP feat, GP gq, GP gk) {
  int blk = blockIdx.x;
  if (blk < 32)        gemm_dispatch(sat, blk);
  else if (blk < 160)  gemm_dispatch(pos, blk - 32);
  else if (blk < 288)  gemm_dispatch(feat, blk - 160);
  else if (blk < 320)  gemm_dispatch(gq, blk - 288);
  else                 gemm_dispatch(gk, blk - 320);
}
// L2: kv(64) q(128) geo2q(32) geo2k(8) = 232 blocks
__global__ __launch_bounds__(256) void k_gemm_L2(GP kv, GP q, GP gq, GP gk) {
  int blk = blockIdx.x;
  if (blk < 64)        gemm_dispatch(kv, blk);
  else if (blk < 192)  gemm_dispatch(q, blk - 64);
  else if (blk < 224)  gemm_dispatch(gq, blk - 192);
  else                 gemm_dispatch(gk, blk - 224);
}

// ================= merged LayerNorms =================
// blocks: [0,1024) front chain, [1024,1280) sat D=512, [1280,2560) geo D=128
__global__ __launch_bounds__(256) void k_ln_all(
    const u16* __restrict__ feat_pre, const u16* __restrict__ pos,
    const float* __restrict__ fg, const float* __restrict__ fb,
    const float* __restrict__ qg, const float* __restrict__ qb2,
    u16* __restrict__ q_embed,
    const u16* __restrict__ satf_pre, const float* __restrict__ sg,
    const float* __restrict__ sb, u16* __restrict__ satf,
    const u16* __restrict__ ginq, const u16* __restrict__ gink,
    const float* __restrict__ ggq, const float* __restrict__ gbq,
    const float* __restrict__ ggk, const float* __restrict__ gbk,
    u16* __restrict__ goutq, u16* __restrict__ goutk) {
  int blk = blockIdx.x;
  int w = threadIdx.x >> 6, lane = threadIdx.x & 63;
  if (blk < 1024) {
    int row = blk * 4 + w;
    bf8v v = *(const bf8v*)(feat_pre + (size_t)row * 512 + lane * 8);
    float x[8];
#pragma unroll
    for (int e = 0; e < 8; ++e) x[e] = bf2f((u16)v[e]);
    float s = 0.f, q = 0.f;
#pragma unroll
    for (int e = 0; e < 8; ++e) { s += x[e]; q += x[e] * x[e]; }
#pragma unroll
    for (int mm = 1; mm < 64; mm <<= 1) { s += __shfl_xor(s, mm); q += __shfl_xor(q, mm); }
    float mean = s / 512.f, var = q / 512.f - mean * mean;
    float rstd = rsqrtf(var + 1e-5f);
    bf8v vp = *(const bf8v*)(pos + (size_t)row * 512 + lane * 8);
#pragma unroll
    for (int e = 0; e < 8; ++e)
      x[e] = (x[e] - mean) * rstd * fg[lane * 8 + e] + fb[lane * 8 + e] + bf2f((u16)vp[e]);
    s = 0.f; q = 0.f;
#pragma unroll
    for (int e = 0; e < 8; ++e) { s += x[e]; q += x[e] * x[e]; }
#pragma unroll
    for (int mm = 1; mm < 64; mm <<= 1) { s += __shfl_xor(s, mm); q += __shfl_xor(q, mm); }
    mean = s / 512.f; var = q / 512.f - mean * mean;
    rstd = rsqrtf(var + 1e-5f);
    bf8v ov;
#pragma unroll
    for (int e = 0; e < 8; ++e)
      ov[e] = (short)f2bf((x[e] - mean) * rstd * qg[lane * 8 + e] + qb2[lane * 8 + e]);
    *(bf8v*)(q_embed + (size_t)row * 512 + lane * 8) = ov;
  } else if (blk < 1280) {
    int row = (blk - 1024) * 4 + w;
    bf8v v = *(const bf8v*)(satf_pre + (size_t)row * 512 + lane * 8);
    float x[8];
#pragma unroll
    for (int e = 0; e < 8; ++e) x[e] = bf2f((u16)v[e]);
    float s = 0.f, q = 0.f;
#pragma unroll
    for (int e = 0; e < 8; ++e) { s += x[e]; q += x[e] * x[e]; }
#pragma unroll
    for (int mm = 1; mm < 64; mm <<= 1) { s += __shfl_xor(s, mm); q += __shfl_xor(q, mm); }
    float mean = s / 512.f, var = q / 512.f - mean * mean;
    float rstd = rsqrtf(var + 1e-5f);
    bf8v ov;
#pragma unroll
    for (int e = 0; e < 8; ++e)
      ov[e] = (short)f2bf((x[e] - mean) * rstd * sg[lane * 8 + e] + sb[lane * 8 + e]);
    *(bf8v*)(satf + (size_t)row * 512 + lane * 8) = ov;
  } else {
    int row = (blk - 1280) * 4 + w;
    const u16* in; const float *g, *b; u16* out;
    if (row < 4096) { in = ginq; g = ggq; b = gbq; out = goutq; }
    else { row -= 4096; in = gink; g = ggk; b = gbk; out = goutk; }
    uint32_t v = *(const uint32_t*)(in + (size_t)row * 128 + lane * 2);
    float x0 = bf2f((u16)(v & 0xffff)), x1 = bf2f((u16)(v >> 16));
    float s = x0 + x1, q = x0 * x0 + x1 * x1;
#pragma unroll
    for (int mm = 1; mm < 64; mm <<= 1) { s += __shfl_xor(s, mm); q += __shfl_xor(q, mm); }
    float mean = s / 128.f, var = q / 128.f - mean * mean;
    float rstd = rsqrtf(var + 1e-5f);
    u16 o0 = f2bf((x0 - mean) * rstd * g[lane * 2] + b[lane * 2]);
    u16 o1 = f2bf((x1 - mean) * rstd * g[lane * 2 + 1] + b[lane * 2 + 1]);
    *(uint32_t*)(out + (size_t)row * 128 + lane * 2) = (uint32_t)o0 | ((uint32_t)o1 << 16);
  }
}

// ================= merged prep: Q/K aug (rope+geo+xy) + V transpose =================
// blocks: [0,10240) qkprep, [10240,10368) vt
__global__ __launch_bounds__(256) void k_prep(
    const u16* __restrict__ qlin, const u16* __restrict__ qglin,
    const float* __restrict__ qxy, u16* __restrict__ Qaug_,
    const u16* __restrict__ klin, const u16* __restrict__ kglin,
    const float* __restrict__ kxy, u16* __restrict__ Kaug_,
    float* __restrict__ kk2_, u16* __restrict__ VT) {
  __shared__ u16 sT[64][72];
  int blk = blockIdx.x;
  if (blk < 10240) {
    int gid = blk * 4 + (threadIdx.x >> 6);
    int lane = threadIdx.x & 63;
    const u16 *lin, *glin; const float* xy; u16* aug;
    int lstride, n, h, isQ; float scm, scg;
    if (gid < NF * 8) {
      lin = qlin; glin = qglin; xy = qxy; aug = Qaug_;
      lstride = MD; n = gid >> 3; h = gid & 7; isQ = 1;
      scm = 0.125f * L2E; scg = 0.25f * L2E;
    } else {
      gid -= NF * 8;
      lin = klin; glin = kglin; xy = kxy; aug = Kaug_;
      lstride = 1024; n = gid >> 3; h = gid & 7; isQ = 0;
      scm = 1.f; scg = 1.f;
    }
    float val = bf2f(lin[(size_t)n * lstride + h * 64 + lane]);
    float part = __shfl_xor(val, 8);
    float x = xy[n * 2], y = xy[n * 2 + 1];
    float outv = val;
    if (lane < 32) {
      float coord = (lane < 16) ? x : y;
      int j = lane & 7;
      float th = coord * __expf(-(float)j * 1.1512925465f);   // 10000^(-j/8)
      float sn, cs;
      __sincosf(th, &sn, &cs);
      outv = ((lane & 8) == 0) ? (val * cs - part * sn) : (part * sn + val * cs);
    }
    u16* dst = aug + (size_t)(h * (isQ ? NF : NS) + n) * DA;
    dst[lane] = f2bf(outv * scm);
    if (lane < 16) {
      float gv = bf2f(glin[(size_t)n * GHID + h * 16 + lane]);
      dst[64 + lane] = f2bf(gv * scg);
    } else if (lane == 16) {
      dst[80] = f2bf(S2L * x);
    } else if (lane == 17) {
      dst[81] = f2bf(S2L * y);
    } else if (lane == 18) {
      dst[82] = 0;
      if (!isQ && h == 0) kk2_[n] = L2E * (x * x + y * y);
    } else if (lane < 32) {
      dst[64 + lane] = 0;
    }
  } else {
    int lb = blk - 10240;
    int n0 = (lb & 15) * 64, h = lb >> 4;
    int t = threadIdx.x;
    int r = t >> 2, c = (t & 3) * 16;
    const u16* src = klin + (size_t)(n0 + r) * 1024 + 512 + h * 64 + c;
    *(bf8v*)&sT[r][c]     = *(const bf8v*)src;
    *(bf8v*)&sT[r][c + 8] = *(const bf8v*)(src + 8);
    __syncthreads();
    int d = t >> 2, nc = (t & 3) * 16;
    bf8v p0, p1;
#pragma unroll
    for (int e = 0; e < 8; ++e) { p0[e] = (short)sT[nc + e][d]; p1[e] = (short)sT[nc + 8 + e][d]; }
    u16* dst = VT + (size_t)(h * 64 + d) * 1024 + n0 + nc;
    *(bf8v*)dst = p0;
    *(bf8v*)(dst + 8) = p1;
  }
}

// ================= fused flash attention (unchanged) =================
__global__ __launch_bounds__(256, 4) void k_flash(const u16* __restrict__ Qa,
                                                  const u16* __restrict__ Ka,
                                                  const u16* __restrict__ VT,
                                                  const float* __restrict__ kk2,
                                                  float* __restrict__ Opart,
                                                  float2* __restrict__ ml) {
  const int h = blockIdx.y, qb = blockIdx.x, sp = blockIdx.z;
  const int tid = threadIdx.x, w = tid >> 6, lane = tid & 63;
  const int l16 = lane & 15, lh = lane >> 4;
  __shared__ u16 sK[64][104];
  __shared__ u16 sV[64][72];
  __shared__ u16 sP[4][16][72];
  __shared__ float sKK[512];

  ((float2*)sKK)[tid] = ((const float2*)(kk2 + sp * 512))[tid];

  const int qrow = qb * 64 + w * 16 + l16;
  bf8v qf[3];
#pragma unroll
  for (int c = 0; c < 3; ++c)
    qf[c] = *(const bf8v*)(Qa + (size_t)(h * NF + qrow) * DA + c * 32 + lh * 8);

  bf8v ONES;
#pragma unroll
  for (int i = 0; i < 8; ++i) ONES[i] = (short)0x3F80;

  const int crow = qb * 64 + w * 16 + (lh << 2);
  float m_run[4], l_run[4];
  f4v accO[4];
#pragma unroll
  for (int r = 0; r < 4; ++r) { m_run[r] = -1e30f; l_run[r] = 0.f; }
#pragma unroll
  for (int d = 0; d < 4; ++d) accO[d] = (f4v){0.f, 0.f, 0.f, 0.f};

  const int kt0 = sp * 8;
  bf8v kreg[3], vreg[2];
  auto sload = [&](int t8) {
    int kb = (kt0 + t8) * 64;
#pragma unroll
    for (int i = 0; i < 3; ++i) {
      int c = tid + i * 256; int r = c / 12, off = (c % 12) * 8;
      kreg[i] = *(const bf8v*)(Ka + ((size_t)(h * NS) + kb + r) * DA + off);
    }
#pragma unroll
    for (int i = 0; i < 2; ++i) {
      int c = tid + i * 256; int d = c >> 3, off = (c & 7) * 8;
      vreg[i] = *(const bf8v*)(VT + ((size_t)(h * HD) + d) * NS + kb + off);
    }
  };
  auto swrite = [&]() {
#pragma unroll
    for (int i = 0; i < 3; ++i) {
      int c = tid + i * 256; int r = c / 12, off = (c % 12) * 8;
      *(bf8v*)&sK[r][off] = kreg[i];
    }
#pragma unroll
    for (int i = 0; i < 2; ++i) {
      int c = tid + i * 256; int d = c >> 3, off = (c & 7) * 8;
      *(bf8v*)&sV[d][off] = vreg[i];
    }
  };

  sload(0); swrite();
  __syncthreads();
  for (int t8 = 0; t8 < 8; ++t8) {
    if (t8 < 7) sload(t8 + 1);
    float p[4][4];
    float rmax[4] = {-1e30f, -1e30f, -1e30f, -1e30f};
#pragma unroll
    for (int j = 0; j < 4; ++j) {
      f4v s4 = (f4v){0.f, 0.f, 0.f, 0.f};
#pragma unroll
      for (int c = 0; c < 3; ++c) {
        bf8v kf = *(const bf8v*)&sK[j * 16 + l16][c * 32 + lh * 8];
        s4 = mfma16(qf[c], kf, s4);
      }
      float ck = sKK[t8 * 64 + j * 16 + l16];
#pragma unroll
      for (int r = 0; r < 4; ++r) {
        float sv = s4[r] - ck;
        p[j][r] = sv;
        rmax[r] = fmaxf(rmax[r], sv);
      }
    }
#pragma unroll
    for (int r = 0; r < 4; ++r)
#pragma unroll
      for (int mm = 1; mm < 16; mm <<= 1)
        rmax[r] = fmaxf(rmax[r], __shfl_xor(rmax[r], mm));
    bool within = (rmax[0] <= m_run[0] + 8.f) && (rmax[1] <= m_run[1] + 8.f) &&
                  (rmax[2] <= m_run[2] + 8.f) && (rmax[3] <= m_run[3] + 8.f);
    if (!__all(within)) {
      float sc[4];
#pragma unroll
      for (int r = 0; r < 4; ++r) {
        float mnew = fmaxf(m_run[r], rmax[r]);
        sc[r] = exp2f(m_run[r] - mnew);
        m_run[r] = mnew;
      }
#pragma unroll
      for (int r = 0; r < 4; ++r) {
        l_run[r] *= sc[r];
#pragma unroll
        for (int d = 0; d < 4; ++d) accO[d][r] *= sc[r];
      }
    }
#pragma unroll
    for (int j = 0; j < 4; ++j)
#pragma unroll
      for (int r = 0; r < 4; ++r) {
        p[j][r] = exp2f(p[j][r] - m_run[r]);
        sP[w][(lh << 2) + r][j * 16 + l16] = f2bf(p[j][r]);
      }
    bf8v pf0 = *(const bf8v*)&sP[w][l16][lh * 8];
    bf8v pf1 = *(const bf8v*)&sP[w][l16][32 + lh * 8];
    f4v ls = (f4v){0.f, 0.f, 0.f, 0.f};
    ls = mfma16(pf0, ONES, ls);
    ls = mfma16(pf1, ONES, ls);
#pragma unroll
    for (int r = 0; r < 4; ++r) l_run[r] += ls[r];
#pragma unroll
    for (int c = 0; c < 2; ++c) {
      bf8v pf = (c == 0) ? pf0 : pf1;
#pragma unroll
      for (int d = 0; d < 4; ++d) {
        bf8v vf = *(const bf8v*)&sV[d * 16 + l16][c * 32 + lh * 8];
        accO[d] = mfma16(pf, vf, accO[d]);
      }
    }
    __syncthreads();
    if (t8 < 7) swrite();
    __syncthreads();
  }
  size_t obase = (size_t)(sp * 8 + h) * NF + crow;
#pragma unroll
  for (int d = 0; d < 4; ++d)
#pragma unroll
    for (int r = 0; r < 4; ++r)
      Opart[(obase + r) * 64 + d * 16 + l16] = accO[d][r];
  if (l16 == 0) {
#pragma unroll
    for (int r = 0; r < 4; ++r) ml[obase + r] = make_float2(m_run[r], l_run[r]);
  }
}

// ================= combine the 2 NS-splits =================
__global__ void k_combine(const float* __restrict__ Opart, const float2* __restrict__ ml,
                          float* __restrict__ out) {
  int i4 = blockIdx.x * 256 + threadIdx.x;
  int n = i4 >> 7;
  int c4 = i4 & 127, h = c4 >> 4, d4 = c4 & 15;
  float2 a = ml[(size_t)h * NF + n];
  float2 b = ml[(size_t)(8 + h) * NF + n];
  float m = fmaxf(a.x, b.x);
  float w1 = exp2f(a.x - m), w2 = exp2f(b.x - m);
  float rl = 1.f / (a.y * w1 + b.y * w2);
  float4 o1 = ((const float4*)(Opart + ((size_t)h * NF + n) * 64))[d4];
  float4 o2 = ((const float4*)(Opart + ((size_t)(8 + h) * NF + n) * 64))[d4];
  float4 r;
  r.x = (o1.x * w1 + o2.x * w2) * rl;
  r.y = (o1.y * w1 + o2.y * w2) * rl;
  r.z = (o1.z * w1 + o2.z * w2) * rl;
  r.w = (o1.w * w1 + o2.w * w2) * rl;
  ((float4*)out)[i4] = r;
}

extern "C" void kernel_launch(void* const* d_in, const int* in_sizes, int n_in,
                              void* d_out, int out_size, void* d_ws, size_t ws_size,
                              hipStream_t stream) {
  (void)in_sizes; (void)n_in; (void)out_size; (void)ws_size;
  const float* front_feat = (const float*)d_in[0];
  const float* bev_xy     = (const float*)d_in[1];
  const float* sat_tokens = (const float*)d_in[2];
  const float* sat_xy     = (const float*)d_in[3];
  const float* plucker    = (const float*)d_in[4];
  const float* pos_w1 = (const float*)d_in[5];
  const float* pos_b1 = (const float*)d_in[6];
  const float* pos_w2 = (const float*)d_in[7];
  const float* pos_b2 = (const float*)d_in[8];
  const float* fa_w   = (const float*)d_in[9];
  const float* fa_b   = (const float*)d_in[10];
  const float* fa_ln_g = (const float*)d_in[11];
  const float* fa_ln_b = (const float*)d_in[12];
  const float* qn_g   = (const float*)d_in[13];
  const float* qn_b   = (const float*)d_in[14];
  const float* sa_w   = (const float*)d_in[15];
  const float* sa_b   = (const float*)d_in[16];
  const float* sa_ln_g = (const float*)d_in[17];
  const float* sa_ln_b = (const float*)d_in[18];
  const float* wq = (const float*)d_in[19];
  const float* bq = (const float*)d_in[20];
  const float* wk = (const float*)d_in[21];
  const float* bk = (const float*)d_in[22];
  const float* wv = (const float*)d_in[23];
  const float* bv = (const float*)d_in[24];
  const float* plk_w1 = (const float*)d_in[25];
  const float* plk_b1 = (const float*)d_in[26];
  const float* plk_w2 = (const float*)d_in[27];
  const float* plk_b2 = (const float*)d_in[28];
  const float* sxy_w1 = (const float*)d_in[29];
  const float* sxy_b1 = (const float*)d_in[30];
  const float* sxy_w2 = (const float*)d_in[31];
  const float* sxy_b2 = (const float*)d_in[32];
  const float* gqn_g = (const float*)d_in[33];
  const float* gqn_b = (const float*)d_in[34];
  const float* gkn_g = (const float*)d_in[35];
  const float* gkn_b = (const float*)d_in[36];
  const float* wqg = (const float*)d_in[37];
  const float* bqg = (const float*)d_in[38];
  const float* wkg = (const float*)d_in[39];
  const float* bkg = (const float*)d_in[40];

  char* ws = (char*)d_ws;
  size_t off = 0;
  auto alloc = [&](size_t bytes) {
    size_t r = off;
    off += (bytes + 255) & ~(size_t)255;
    return r;
  };
  u16*   wpool   = (u16*)(ws + alloc((size_t)TOTW * 2));
  float* bkv     = (float*)(ws + alloc(1024 * 4));
  u16*   ffT     = (u16*)(ws + alloc((size_t)NF * 320 * 2));
  u16*   pos_h   = (u16*)(ws + alloc((size_t)NF * MD * 2));
  u16*   plk_h   = (u16*)(ws + alloc((size_t)NF * GHID * 2));
  u16*   sxy_h   = (u16*)(ws + alloc((size_t)NS * GHID * 2));
  u16*   pos     = (u16*)(ws + alloc((size_t)NF * MD * 2));
  u16*   feat_pre= (u16*)(ws + alloc((size_t)NF * MD * 2));
  u16*   satf_pre= (u16*)(ws + alloc((size_t)NS * MD * 2));
  u16*   satf    = (u16*)(ws + alloc((size_t)NS * MD * 2));
  u16*   q_embed = (u16*)(ws + alloc((size_t)NF * MD * 2));
  u16*   plk2    = (u16*)(ws + alloc((size_t)NF * GHID * 2));
  u16*   sxy2    = (u16*)(ws + alloc((size_t)NS * GHID * 2));
  u16*   q_lin   = (u16*)(ws + alloc((size_t)NF * MD * 2));
  u16*   kv_lin  = (u16*)(ws + alloc((size_t)NS * 1024 * 2));
  u16*   Qaug    = (u16*)(ws + alloc((size_t)8 * NF * DA * 2));
  u16*   Kaug    = (u16*)(ws + alloc((size_t)8 * NS * DA * 2));
  u16*   VT      = (u16*)(ws + alloc((size_t)8 * HD * NS * 2));
  float* kk2     = (float*)(ws + alloc((size_t)NS * 4));
  float* Opart   = (float*)(ws + alloc((size_t)2 * 8 * NF * 64 * 4));
  float2* mlb    = (float2*)(ws + alloc((size_t)2 * 8 * NF * 8));
  // aliases (producer dead before alias written)
  u16* plk_ln = plk_h;
  u16* sgf    = sxy_h;
  u16* qg_lin = plk2;
  u16* kg_lin = sxy2;

  dim3 b256(256);
  // L0: convert + ffT + silus
  k_l0<<<dim3(13793), b256, 0, stream>>>(
      pos_w2, fa_w, sa_w, wq, wk, wv, plk_w2, sxy_w2, wqg, wkg, sat_tokens,
      wpool, bk, bv, bkv, front_feat, ffT,
      bev_xy, pos_w1, pos_b1, pos_h,
      plucker, plk_w1, plk_b1, plk_h,
      sat_xy, sxy_w1, sxy_b1, sxy_h);

  // L1 GEMMs (128x128 tiles)
  GP gsat {wpool + OFF_SATT, wpool + OFF_SAW, sa_b, satf_pre, 768, 512, 1024};
  GP gpos {pos_h, wpool + OFF_POSW2, pos_b2, pos, 512, 512, 4096};
  GP gfeat{ffT, wpool + OFF_FAW, fa_b, feat_pre, 320, 512, 4096};
  GP ggq1 {plk_h, wpool + OFF_PLKW2, plk_b2, plk2, 128, 128, 4096};
  GP ggk1 {sxy_h, wpool + OFF_SXYW2, sxy_b2, sxy2, 128, 128, 1024};
  k_gemm_L1<<<dim3(328), b256, 0, stream>>>(gsat, gpos, gfeat, ggq1, ggk1);

  // LNs
  k_ln_all<<<dim3(2560), b256, 0, stream>>>(
      feat_pre, pos, fa_ln_g, fa_ln_b, qn_g, qn_b, q_embed,
      satf_pre, sa_ln_g, sa_ln_b, satf,
      plk2, sxy2, gqn_g, gqn_b, gkn_g, gkn_b, plk_ln, sgf);

  // L2 GEMMs
  GP gkv {satf, wpool + OFF_WKV, bkv, kv_lin, 512, 1024, 1024};
  GP gq  {q_embed, wpool + OFF_WQ, bq, q_lin, 512, 512, 4096};
  GP ggq2{plk_ln, wpool + OFF_WQG, bqg, qg_lin, 128, 128, 4096};
  GP ggk2{sgf, wpool + OFF_WKG, bkg, kg_lin, 128, 128, 1024};
  k_gemm_L2<<<dim3(232), b256, 0, stream>>>(gkv, gq, ggq2, ggk2);

  // prep (qk aug + vt)
  k_prep<<<dim3(10368), b256, 0, stream>>>(
      q_lin, qg_lin, bev_xy, Qaug, kv_lin, kg_lin, sat_xy, Kaug, kk2, VT);

  k_flash<<<dim3(NF / 64, 8, 2), b256, 0, stream>>>(Qaug, Kaug, VT, kk2, Opart, mlb);
  k_combine<<<dim3(NF * MD / 4 / 256), b256, 0, stream>>>(Opart, mlb, (float*)d_out);
}

// Round 7
// 87.013 us; speedup vs baseline: 1.1941x; 1.1941x over previous
//
#include <hip/hip_runtime.h>
#include <hip/hip_bf16.h>
#include <stdint.h>

// Problem constants
#define NF 4096
#define NS 1024
#define MD 512
#define HD 64
#define DA 96
#define GHID 128

#define L2E 1.44269504f          // log2(e)
#define S2L 1.6986436f           // sqrt(2*log2e)  (LAMBDA_GEO=1)
#define SMAX 12.0f               // static softmax offset (|S*log2e| <~ 30 by construction)

typedef unsigned short u16;
typedef __attribute__((ext_vector_type(8))) short bf8v;   // 8 bf16
typedef __attribute__((ext_vector_type(4))) float f4v;

__device__ __forceinline__ u16 f2bf(float f) {
  __hip_bfloat16 h = __float2bfloat16(f);
  return __builtin_bit_cast(u16, h);
}
__device__ __forceinline__ float bf2f(u16 u) {
  union { unsigned u; float f; } v; v.u = ((unsigned)u) << 16; return v.f;
}
__device__ __forceinline__ f4v mfma16(bf8v a, bf8v b, f4v c) {
  return __builtin_amdgcn_mfma_f32_16x16x32_bf16(a, b, c, 0, 0, 0);
}
__device__ __forceinline__ void gld16(const void* g, void* l) {
  __builtin_amdgcn_global_load_lds(
      (const __attribute__((address_space(1))) unsigned int*)g,
      (__attribute__((address_space(3))) unsigned int*)l, 16, 0, 0);
}

// weight pool offsets (bf16 elements)
#define OFF_POSW2 0
#define OFF_FAW   262144
#define OFF_SAW   425984
#define OFF_WQ    819200
#define OFF_WKV   1081344
#define OFF_PLKW2 1605632
#define OFF_SXYW2 1622016
#define OFF_WQG   1638400
#define OFF_WKG   1654784
#define OFF_SATT  1671168
#define TOTW      2457600

// ================= L0: convert weights + ffT transpose + 3 silu MLPs =================
// blocks: [0,2401) convert, [2401,3041) ffT, [3041,13793) silu
__global__ __launch_bounds__(256) void k_l0(
    const float* __restrict__ s0, const float* __restrict__ s1,
    const float* __restrict__ s2, const float* __restrict__ s3,
    const float* __restrict__ s4, const float* __restrict__ s5,
    const float* __restrict__ s6, const float* __restrict__ s7,
    const float* __restrict__ s8, const float* __restrict__ s9,
    const float* __restrict__ s10, u16* __restrict__ pool,
    const float* __restrict__ bk, const float* __restrict__ bv,
    float* __restrict__ bkv,
    const float* __restrict__ ff, u16* __restrict__ ffT,
    const float* __restrict__ in0, const float* __restrict__ w0,
    const float* __restrict__ b0, u16* __restrict__ o0,
    const float* __restrict__ in1, const float* __restrict__ w1,
    const float* __restrict__ b1, u16* __restrict__ o1,
    const float* __restrict__ in2, const float* __restrict__ w2,
    const float* __restrict__ b2, u16* __restrict__ o2) {
  __shared__ u16 sT[32][72];
  int blk = blockIdx.x, t = threadIdx.x;
  if (blk < 2401) {
    int i4 = blk * 256 + t;
    if (i4 < TOTW / 4) {
      int idx = i4 * 4;
      const float* src; int off;
      if      (idx < OFF_FAW)   { src = s0;  off = OFF_POSW2; }
      else if (idx < OFF_SAW)   { src = s1;  off = OFF_FAW; }
      else if (idx < OFF_WQ)    { src = s2;  off = OFF_SAW; }
      else if (idx < OFF_WKV)   { src = s3;  off = OFF_WQ; }
      else if (idx < 1343488)   { src = s4;  off = OFF_WKV; }
      else if (idx < OFF_PLKW2) { src = s5;  off = 1343488; }
      else if (idx < OFF_SXYW2) { src = s6;  off = OFF_PLKW2; }
      else if (idx < OFF_WQG)   { src = s7;  off = OFF_SXYW2; }
      else if (idx < OFF_WKG)   { src = s8;  off = OFF_WQG; }
      else if (idx < OFF_SATT)  { src = s9;  off = OFF_WKG; }
      else                      { src = s10; off = OFF_SATT; }
      float4 v = *(const float4*)(src + (idx - off));
      ushort4 o;
      o.x = f2bf(v.x); o.y = f2bf(v.y); o.z = f2bf(v.z); o.w = f2bf(v.w);
      *(ushort4*)(pool + idx) = o;
    } else if (i4 < TOTW / 4 + 256) {
      int j = (i4 - TOTW / 4) * 4;
#pragma unroll
      for (int e = 0; e < 4; ++e) {
        int b = j + e;
        bkv[b] = (b < 512) ? bk[b] : bv[b - 512];
      }
    }
  } else if (blk < 3041) {
    int lb = blk - 2401;
    int n0 = (lb & 63) * 64, c0 = (lb >> 6) * 32;
    {
      int cr = t >> 3, nc = (t & 7) * 8;
      const float* src = ff + (size_t)(c0 + cr) * NF + n0 + nc;
      float4 v0 = *(const float4*)src, v1 = *(const float4*)(src + 4);
      bf8v p;
      p[0]=(short)f2bf(v0.x); p[1]=(short)f2bf(v0.y); p[2]=(short)f2bf(v0.z); p[3]=(short)f2bf(v0.w);
      p[4]=(short)f2bf(v1.x); p[5]=(short)f2bf(v1.y); p[6]=(short)f2bf(v1.z); p[7]=(short)f2bf(v1.w);
      *(bf8v*)&sT[cr][nc] = p;
    }
    __syncthreads();
    {
      int r = t >> 2, cc = (t & 3) * 8;
      bf8v p;
#pragma unroll
      for (int e = 0; e < 8; ++e) p[e] = (short)sT[cc + e][r];
      *(bf8v*)(ffT + (size_t)(n0 + r) * 320 + c0 + cc) = p;
    }
  } else {
    int lb = blk - 3041;
    const float *in, *w, *b; u16* o; int mlog, K, idx;
    if (lb < 8192)       { in = in0; w = w0; b = b0; o = o0; mlog = 9; K = 2; idx = lb * 256 + t; }
    else if (lb < 10240) { in = in1; w = w1; b = b1; o = o1; mlog = 7; K = 6; idx = (lb - 8192) * 256 + t; }
    else                 { in = in2; w = w2; b = b2; o = o2; mlog = 7; K = 2; idx = (lb - 10240) * 256 + t; }
    int M = 1 << mlog;
    int n = idx >> mlog, m = idx & (M - 1);
    float acc = b[m];
    for (int k = 0; k < K; ++k) acc += in[n * K + k] * w[m * K + k];
    o[idx] = f2bf(acc / (1.f + __expf(-acc)));
  }
}

// ================= bf16 MFMA GEMM body, 64x64 tile, BK=64, dbuf LDS (r5 version) =================
__device__ __forceinline__ void gemm_body(const u16* __restrict__ A, const u16* __restrict__ W,
                                          const float* __restrict__ bias, u16* __restrict__ out,
                                          int m0, int n0, int N, int K) {
  constexpr int BM = 64, BN = 64;
  constexpr int MR = 2, NR = 2;        // per-wave 32x32
  __shared__ u16 sA[2][BM * 64];
  __shared__ u16 sB[2][BN * 64];
  const int tid = threadIdx.x, w = tid >> 6, lane = tid & 63;
  const int l16 = lane & 15, lh = lane >> 4;
  const int wr = w >> 1, wc = w & 1;

  f4v acc[MR][NR];
#pragma unroll
  for (int m = 0; m < MR; ++m)
#pragma unroll
    for (int j = 0; j < NR; ++j) acc[m][j] = (f4v){0.f, 0.f, 0.f, 0.f};

  auto stageA = [&](int buf, int k0) {
#pragma unroll
    for (int i = 0; i < 2; ++i) {
      int c = i * 256 + tid;
      int row = c >> 3, cp = c & 7;
      int sc_ = cp ^ (row & 7);
      gld16(A + (size_t)(m0 + row) * K + k0 + sc_ * 8, &sA[buf][c * 8]);
    }
  };
  auto stageB = [&](int buf, int k0) {
#pragma unroll
    for (int i = 0; i < 2; ++i) {
      int c = i * 256 + tid;
      int row = c >> 3, cp = c & 7;
      int sc_ = cp ^ (row & 7);
      gld16(W + (size_t)(n0 + row) * K + k0 + sc_ * 8, &sB[buf][c * 8]);
    }
  };

  stageA(0, 0); stageB(0, 0);
  __syncthreads();
  const int NK = K >> 6;
  for (int ks = 0; ks < NK; ++ks) {
    int nb = ks & 1;
    if (ks + 1 < NK) { stageA(nb ^ 1, (ks + 1) * 64); stageB(nb ^ 1, (ks + 1) * 64); }
#pragma unroll
    for (int kk = 0; kk < 2; ++kk) {
      bf8v af[MR], bfr[NR];
#pragma unroll
      for (int m = 0; m < MR; ++m) {
        int row = wr * 32 + m * 16 + l16;
        int cp = (kk * 4 + lh) ^ (row & 7);
        af[m] = *(const bf8v*)&sA[nb][row * 64 + cp * 8];
      }
#pragma unroll
      for (int j = 0; j < NR; ++j) {
        int row = wc * 32 + j * 16 + l16;
        int cp = (kk * 4 + lh) ^ (row & 7);
        bfr[j] = *(const bf8v*)&sB[nb][row * 64 + cp * 8];
      }
#pragma unroll
      for (int m = 0; m < MR; ++m)
#pragma unroll
        for (int j = 0; j < NR; ++j) acc[m][j] = mfma16(af[m], bfr[j], acc[m][j]);
    }
    __syncthreads();
  }
#pragma unroll
  for (int m = 0; m < MR; ++m) {
    int grow = m0 + wr * 32 + m * 16 + (lh << 2);
#pragma unroll
    for (int j = 0; j < NR; ++j) {
      int gcol = n0 + wc * 32 + j * 16 + l16;
      float bv = bias ? bias[gcol] : 0.f;
#pragma unroll
      for (int r = 0; r < 4; ++r)
        out[(size_t)(grow + r) * N + gcol] = f2bf(acc[m][j][r] + bv);
    }
  }
}

struct GP { const u16* A; const u16* W; const float* bias; u16* out; int K; int N; int M; };

__device__ __forceinline__ void gemm_dispatch(const GP& g, int blk) {
  int mt = g.M >> 6;
  int m0 = (blk % mt) * 64, n0 = (blk / mt) * 64;
  gemm_body(g.A, g.W, g.bias, g.out, m0, n0, g.N, g.K);
}

// L1: pos(512) feat(512) sat(128) geo1q(128) geo1k(32) = 1312 blocks
__global__ __launch_bounds__(256) void k_gemm_L1(GP a, GP b, GP c, GP d, GP e) {
  int blk = blockIdx.x;
  if (blk < 512)       gemm_dispatch(a, blk);
  else if (blk < 1024) gemm_dispatch(b, blk - 512);
  else if (blk < 1152) gemm_dispatch(c, blk - 1024);
  else if (blk < 1280) gemm_dispatch(d, blk - 1152);
  else                 gemm_dispatch(e, blk - 1280);
}
// L2: q(512) kv(256) geo2q(128) geo2k(32) = 928 blocks
__global__ __launch_bounds__(256) void k_gemm_L2(GP a, GP b, GP c, GP d) {
  int blk = blockIdx.x;
  if (blk < 512)      gemm_dispatch(a, blk);
  else if (blk < 768) gemm_dispatch(b, blk - 512);
  else if (blk < 896) gemm_dispatch(c, blk - 768);
  else                gemm_dispatch(d, blk - 896);
}

// ================= merged LayerNorms =================
// blocks: [0,1024) front chain, [1024,1280) sat D=512, [1280,2560) geo D=128
__global__ __launch_bounds__(256) void k_ln_all(
    const u16* __restrict__ feat_pre, const u16* __restrict__ pos,
    const float* __restrict__ fg, const float* __restrict__ fb,
    const float* __restrict__ qg, const float* __restrict__ qb2,
    u16* __restrict__ q_embed,
    const u16* __restrict__ satf_pre, const float* __restrict__ sg,
    const float* __restrict__ sb, u16* __restrict__ satf,
    const u16* __restrict__ ginq, const u16* __restrict__ gink,
    const float* __restrict__ ggq, const float* __restrict__ gbq,
    const float* __restrict__ ggk, const float* __restrict__ gbk,
    u16* __restrict__ goutq, u16* __restrict__ goutk) {
  int blk = blockIdx.x;
  int w = threadIdx.x >> 6, lane = threadIdx.x & 63;
  if (blk < 1024) {
    int row = blk * 4 + w;
    bf8v v = *(const bf8v*)(feat_pre + (size_t)row * 512 + lane * 8);
    float x[8];
#pragma unroll
    for (int e = 0; e < 8; ++e) x[e] = bf2f((u16)v[e]);
    float s = 0.f, q = 0.f;
#pragma unroll
    for (int e = 0; e < 8; ++e) { s += x[e]; q += x[e] * x[e]; }
#pragma unroll
    for (int mm = 1; mm < 64; mm <<= 1) { s += __shfl_xor(s, mm); q += __shfl_xor(q, mm); }
    float mean = s / 512.f, var = q / 512.f - mean * mean;
    float rstd = rsqrtf(var + 1e-5f);
    bf8v vp = *(const bf8v*)(pos + (size_t)row * 512 + lane * 8);
#pragma unroll
    for (int e = 0; e < 8; ++e)
      x[e] = (x[e] - mean) * rstd * fg[lane * 8 + e] + fb[lane * 8 + e] + bf2f((u16)vp[e]);
    s = 0.f; q = 0.f;
#pragma unroll
    for (int e = 0; e < 8; ++e) { s += x[e]; q += x[e] * x[e]; }
#pragma unroll
    for (int mm = 1; mm < 64; mm <<= 1) { s += __shfl_xor(s, mm); q += __shfl_xor(q, mm); }
    mean = s / 512.f; var = q / 512.f - mean * mean;
    rstd = rsqrtf(var + 1e-5f);
    bf8v ov;
#pragma unroll
    for (int e = 0; e < 8; ++e)
      ov[e] = (short)f2bf((x[e] - mean) * rstd * qg[lane * 8 + e] + qb2[lane * 8 + e]);
    *(bf8v*)(q_embed + (size_t)row * 512 + lane * 8) = ov;
  } else if (blk < 1280) {
    int row = (blk - 1024) * 4 + w;
    bf8v v = *(const bf8v*)(satf_pre + (size_t)row * 512 + lane * 8);
    float x[8];
#pragma unroll
    for (int e = 0; e < 8; ++e) x[e] = bf2f((u16)v[e]);
    float s = 0.f, q = 0.f;
#pragma unroll
    for (int e = 0; e < 8; ++e) { s += x[e]; q += x[e] * x[e]; }
#pragma unroll
    for (int mm = 1; mm < 64; mm <<= 1) { s += __shfl_xor(s, mm); q += __shfl_xor(q, mm); }
    float mean = s / 512.f, var = q / 512.f - mean * mean;
    float rstd = rsqrtf(var + 1e-5f);
    bf8v ov;
#pragma unroll
    for (int e = 0; e < 8; ++e)
      ov[e] = (short)f2bf((x[e] - mean) * rstd * sg[lane * 8 + e] + sb[lane * 8 + e]);
    *(bf8v*)(satf + (size_t)row * 512 + lane * 8) = ov;
  } else {
    int row = (blk - 1280) * 4 + w;
    const u16* in; const float *g, *b; u16* out;
    if (row < 4096) { in = ginq; g = ggq; b = gbq; out = goutq; }
    else { row -= 4096; in = gink; g = ggk; b = gbk; out = goutk; }
    uint32_t v = *(const uint32_t*)(in + (size_t)row * 128 + lane * 2);
    float x0 = bf2f((u16)(v & 0xffff)), x1 = bf2f((u16)(v >> 16));
    float s = x0 + x1, q = x0 * x0 + x1 * x1;
#pragma unroll
    for (int mm = 1; mm < 64; mm <<= 1) { s += __shfl_xor(s, mm); q += __shfl_xor(q, mm); }
    float mean = s / 128.f, var = q / 128.f - mean * mean;
    float rstd = rsqrtf(var + 1e-5f);
    u16 o0 = f2bf((x0 - mean) * rstd * g[lane * 2] + b[lane * 2]);
    u16 o1 = f2bf((x1 - mean) * rstd * g[lane * 2 + 1] + b[lane * 2 + 1]);
    *(uint32_t*)(out + (size_t)row * 128 + lane * 2) = (uint32_t)o0 | ((uint32_t)o1 << 16);
  }
}

// ================= merged prep: Q/K aug (rope+geo+xy) + V transpose =================
// blocks: [0,10240) qkprep, [10240,10368) vt
__global__ __launch_bounds__(256) void k_prep(
    const u16* __restrict__ qlin, const u16* __restrict__ qglin,
    const float* __restrict__ qxy, u16* __restrict__ Qaug_,
    const u16* __restrict__ klin, const u16* __restrict__ kglin,
    const float* __restrict__ kxy, u16* __restrict__ Kaug_,
    float* __restrict__ kk2_, u16* __restrict__ VT) {
  __shared__ u16 sT[64][72];
  int blk = blockIdx.x;
  if (blk < 10240) {
    int gid = blk * 4 + (threadIdx.x >> 6);
    int lane = threadIdx.x & 63;
    const u16 *lin, *glin; const float* xy; u16* aug;
    int lstride, n, h, isQ; float scm, scg;
    if (gid < NF * 8) {
      lin = qlin; glin = qglin; xy = qxy; aug = Qaug_;
      lstride = MD; n = gid >> 3; h = gid & 7; isQ = 1;
      scm = 0.125f * L2E; scg = 0.25f * L2E;
    } else {
      gid -= NF * 8;
      lin = klin; glin = kglin; xy = kxy; aug = Kaug_;
      lstride = 1024; n = gid >> 3; h = gid & 7; isQ = 0;
      scm = 1.f; scg = 1.f;
    }
    float val = bf2f(lin[(size_t)n * lstride + h * 64 + lane]);
    float part = __shfl_xor(val, 8);
    float x = xy[n * 2], y = xy[n * 2 + 1];
    float outv = val;
    if (lane < 32) {
      float coord = (lane < 16) ? x : y;
      int j = lane & 7;
      float th = coord * __expf(-(float)j * 1.1512925465f);   // 10000^(-j/8)
      float sn, cs;
      __sincosf(th, &sn, &cs);
      outv = ((lane & 8) == 0) ? (val * cs - part * sn) : (part * sn + val * cs);
    }
    u16* dst = aug + (size_t)(h * (isQ ? NF : NS) + n) * DA;
    dst[lane] = f2bf(outv * scm);
    if (lane < 16) {
      float gv = bf2f(glin[(size_t)n * GHID + h * 16 + lane]);
      dst[64 + lane] = f2bf(gv * scg);
    } else if (lane == 16) {
      dst[80] = f2bf(S2L * x);
    } else if (lane == 17) {
      dst[81] = f2bf(S2L * y);
    } else if (lane == 18) {
      dst[82] = 0;
      // fold static softmax offset SMAX into the per-key term
      if (!isQ && h == 0) kk2_[n] = L2E * (x * x + y * y) + SMAX;
    } else if (lane < 32) {
      dst[64 + lane] = 0;
    }
  } else {
    int lb = blk - 10240;
    int n0 = (lb & 15) * 64, h = lb >> 4;
    int t = threadIdx.x;
    int r = t >> 2, c = (t & 3) * 16;
    const u16* src = klin + (size_t)(n0 + r) * 1024 + 512 + h * 64 + c;
    *(bf8v*)&sT[r][c]     = *(const bf8v*)src;
    *(bf8v*)&sT[r][c + 8] = *(const bf8v*)(src + 8);
    __syncthreads();
    int d = t >> 2, nc = (t & 3) * 16;
    bf8v p0, p1;
#pragma unroll
    for (int e = 0; e < 8; ++e) { p0[e] = (short)sT[nc + e][d]; p1[e] = (short)sT[nc + 8 + e][d]; }
    u16* dst = VT + (size_t)(h * 64 + d) * 1024 + n0 + nc;
    *(bf8v*)dst = p0;
    *(bf8v*)(dst + 8) = p1;
  }
}

// ================= fused flash attention: static-offset softmax (no max tracking) =================
__global__ __launch_bounds__(256, 4) void k_flash(const u16* __restrict__ Qa,
                                                  const u16* __restrict__ Ka,
                                                  const u16* __restrict__ VT,
                                                  const float* __restrict__ kk2,
                                                  float* __restrict__ Opart,
                                                  float* __restrict__ lbuf) {
  const int h = blockIdx.y, qb = blockIdx.x, sp = blockIdx.z;
  const int tid = threadIdx.x, w = tid >> 6, lane = tid & 63;
  const int l16 = lane & 15, lh = lane >> 4;
  __shared__ u16 sK[64][104];
  __shared__ u16 sV[64][72];
  __shared__ u16 sP[4][16][72];
  __shared__ float sKK[512];

  ((float2*)sKK)[tid] = ((const float2*)(kk2 + sp * 512))[tid];

  const int qrow = qb * 64 + w * 16 + l16;
  bf8v qf[3];
#pragma unroll
  for (int c = 0; c < 3; ++c)
    qf[c] = *(const bf8v*)(Qa + (size_t)(h * NF + qrow) * DA + c * 32 + lh * 8);

  bf8v ONES;
#pragma unroll
  for (int i = 0; i < 8; ++i) ONES[i] = (short)0x3F80;

  const int crow = qb * 64 + w * 16 + (lh << 2);
  float l_run[4] = {0.f, 0.f, 0.f, 0.f};
  f4v accO[4];
#pragma unroll
  for (int d = 0; d < 4; ++d) accO[d] = (f4v){0.f, 0.f, 0.f, 0.f};

  const int kt0 = sp * 8;
  bf8v kreg[3], vreg[2];
  auto sload = [&](int t8) {
    int kb = (kt0 + t8) * 64;
#pragma unroll
    for (int i = 0; i < 3; ++i) {
      int c = tid + i * 256; int r = c / 12, off = (c % 12) * 8;
      kreg[i] = *(const bf8v*)(Ka + ((size_t)(h * NS) + kb + r) * DA + off);
    }
#pragma unroll
    for (int i = 0; i < 2; ++i) {
      int c = tid + i * 256; int d = c >> 3, off = (c & 7) * 8;
      vreg[i] = *(const bf8v*)(VT + ((size_t)(h * HD) + d) * NS + kb + off);
    }
  };
  auto swrite = [&]() {
#pragma unroll
    for (int i = 0; i < 3; ++i) {
      int c = tid + i * 256; int r = c / 12, off = (c % 12) * 8;
      *(bf8v*)&sK[r][off] = kreg[i];
    }
#pragma unroll
    for (int i = 0; i < 2; ++i) {
      int c = tid + i * 256; int d = c >> 3, off = (c & 7) * 8;
      *(bf8v*)&sV[d][off] = vreg[i];
    }
  };

  sload(0); swrite();
  __syncthreads();
  for (int t8 = 0; t8 < 8; ++t8) {
    if (t8 < 7) sload(t8 + 1);    // next tile global->reg, lands during compute
    // ---- P = exp2(Qaug.Kaug - (L2E*|k|^2 + SMAX))  (no max tracking) ----
#pragma unroll
    for (int j = 0; j < 4; ++j) {
      f4v s4 = (f4v){0.f, 0.f, 0.f, 0.f};
#pragma unroll
      for (int c = 0; c < 3; ++c) {
        bf8v kf = *(const bf8v*)&sK[j * 16 + l16][c * 32 + lh * 8];
        s4 = mfma16(qf[c], kf, s4);
      }
      float ck = sKK[t8 * 64 + j * 16 + l16];
#pragma unroll
      for (int r = 0; r < 4; ++r) {
        float pv = exp2f(s4[r] - ck);
        sP[w][(lh << 2) + r][j * 16 + l16] = f2bf(pv);
      }
    }
    bf8v pf0 = *(const bf8v*)&sP[w][l16][lh * 8];
    bf8v pf1 = *(const bf8v*)&sP[w][l16][32 + lh * 8];
    f4v ls = (f4v){0.f, 0.f, 0.f, 0.f};
    ls = mfma16(pf0, ONES, ls);
    ls = mfma16(pf1, ONES, ls);
#pragma unroll
    for (int r = 0; r < 4; ++r) l_run[r] += ls[r];
#pragma unroll
    for (int c = 0; c < 2; ++c) {
      bf8v pf = (c == 0) ? pf0 : pf1;
#pragma unroll
      for (int d = 0; d < 4; ++d) {
        bf8v vf = *(const bf8v*)&sV[d * 16 + l16][c * 32 + lh * 8];
        accO[d] = mfma16(pf, vf, accO[d]);
      }
    }
    __syncthreads();              // all waves done reading sK/sV
    if (t8 < 7) swrite();         // regs -> LDS for next tile
    __syncthreads();
  }
  size_t obase = (size_t)(sp * 8 + h) * NF + crow;
#pragma unroll
  for (int d = 0; d < 4; ++d)
#pragma unroll
    for (int r = 0; r < 4; ++r)
      Opart[(obase + r) * 64 + d * 16 + l16] = accO[d][r];
  if (l16 == 0) {
#pragma unroll
    for (int r = 0; r < 4; ++r) lbuf[obase + r] = l_run[r];
  }
}

// ================= combine the 2 NS-splits (equal static offset -> plain sum) =================
__global__ void k_combine(const float* __restrict__ Opart, const float* __restrict__ lbuf,
                          float* __restrict__ out) {
  int i4 = blockIdx.x * 256 + threadIdx.x;
  int n = i4 >> 7;
  int c4 = i4 & 127, h = c4 >> 4, d4 = c4 & 15;
  float l = lbuf[(size_t)h * NF + n] + lbuf[(size_t)(8 + h) * NF + n];
  float rl = 1.f / l;
  float4 o1 = ((const float4*)(Opart + ((size_t)h * NF + n) * 64))[d4];
  float4 o2 = ((const float4*)(Opart + ((size_t)(8 + h) * NF + n) * 64))[d4];
  float4 r;
  r.x = (o1.x + o2.x) * rl;
  r.y = (o1.y + o2.y) * rl;
  r.z = (o1.z + o2.z) * rl;
  r.w = (o1.w + o2.w) * rl;
  ((float4*)out)[i4] = r;
}

extern "C" void kernel_launch(void* const* d_in, const int* in_sizes, int n_in,
                              void* d_out, int out_size, void* d_ws, size_t ws_size,
                              hipStream_t stream) {
  (void)in_sizes; (void)n_in; (void)out_size; (void)ws_size;
  const float* front_feat = (const float*)d_in[0];
  const float* bev_xy     = (const float*)d_in[1];
  const float* sat_tokens = (const float*)d_in[2];
  const float* sat_xy     = (const float*)d_in[3];
  const float* plucker    = (const float*)d_in[4];
  const float* pos_w1 = (const float*)d_in[5];
  const float* pos_b1 = (const float*)d_in[6];
  const float* pos_w2 = (const float*)d_in[7];
  const float* pos_b2 = (const float*)d_in[8];
  const float* fa_w   = (const float*)d_in[9];
  const float* fa_b   = (const float*)d_in[10];
  const float* fa_ln_g = (const float*)d_in[11];
  const float* fa_ln_b = (const float*)d_in[12];
  const float* qn_g   = (const float*)d_in[13];
  const float* qn_b   = (const float*)d_in[14];
  const float* sa_w   = (const float*)d_in[15];
  const float* sa_b   = (const float*)d_in[16];
  const float* sa_ln_g = (const float*)d_in[17];
  const float* sa_ln_b = (const float*)d_in[18];
  const float* wq = (const float*)d_in[19];
  const float* bq = (const float*)d_in[20];
  const float* wk = (const float*)d_in[21];
  const float* bk = (const float*)d_in[22];
  const float* wv = (const float*)d_in[23];
  const float* bv = (const float*)d_in[24];
  const float* plk_w1 = (const float*)d_in[25];
  const float* plk_b1 = (const float*)d_in[26];
  const float* plk_w2 = (const float*)d_in[27];
  const float* plk_b2 = (const float*)d_in[28];
  const float* sxy_w1 = (const float*)d_in[29];
  const float* sxy_b1 = (const float*)d_in[30];
  const float* sxy_w2 = (const float*)d_in[31];
  const float* sxy_b2 = (const float*)d_in[32];
  const float* gqn_g = (const float*)d_in[33];
  const float* gqn_b = (const float*)d_in[34];
  const float* gkn_g = (const float*)d_in[35];
  const float* gkn_b = (const float*)d_in[36];
  const float* wqg = (const float*)d_in[37];
  const float* bqg = (const float*)d_in[38];
  const float* wkg = (const float*)d_in[39];
  const float* bkg = (const float*)d_in[40];

  char* ws = (char*)d_ws;
  size_t off = 0;
  auto alloc = [&](size_t bytes) {
    size_t r = off;
    off += (bytes + 255) & ~(size_t)255;
    return r;
  };
  u16*   wpool   = (u16*)(ws + alloc((size_t)TOTW * 2));
  float* bkv     = (float*)(ws + alloc(1024 * 4));
  u16*   ffT     = (u16*)(ws + alloc((size_t)NF * 320 * 2));
  u16*   pos_h   = (u16*)(ws + alloc((size_t)NF * MD * 2));
  u16*   plk_h   = (u16*)(ws + alloc((size_t)NF * GHID * 2));
  u16*   sxy_h   = (u16*)(ws + alloc((size_t)NS * GHID * 2));
  u16*   pos     = (u16*)(ws + alloc((size_t)NF * MD * 2));
  u16*   feat_pre= (u16*)(ws + alloc((size_t)NF * MD * 2));
  u16*   satf_pre= (u16*)(ws + alloc((size_t)NS * MD * 2));
  u16*   satf    = (u16*)(ws + alloc((size_t)NS * MD * 2));
  u16*   q_embed = (u16*)(ws + alloc((size_t)NF * MD * 2));
  u16*   plk2    = (u16*)(ws + alloc((size_t)NF * GHID * 2));
  u16*   sxy2    = (u16*)(ws + alloc((size_t)NS * GHID * 2));
  u16*   q_lin   = (u16*)(ws + alloc((size_t)NF * MD * 2));
  u16*   kv_lin  = (u16*)(ws + alloc((size_t)NS * 1024 * 2));
  u16*   Qaug    = (u16*)(ws + alloc((size_t)8 * NF * DA * 2));
  u16*   Kaug    = (u16*)(ws + alloc((size_t)8 * NS * DA * 2));
  u16*   VT      = (u16*)(ws + alloc((size_t)8 * HD * NS * 2));
  float* kk2     = (float*)(ws + alloc((size_t)NS * 4));
  float* Opart   = (float*)(ws + alloc((size_t)2 * 8 * NF * 64 * 4));
  float* lbuf    = (float*)(ws + alloc((size_t)2 * 8 * NF * 4));
  // aliases (producer dead before alias written)
  u16* plk_ln = plk_h;
  u16* sgf    = sxy_h;
  u16* qg_lin = plk2;
  u16* kg_lin = sxy2;

  dim3 b256(256);
  // L0: convert + ffT + silus
  k_l0<<<dim3(13793), b256, 0, stream>>>(
      pos_w2, fa_w, sa_w, wq, wk, wv, plk_w2, sxy_w2, wqg, wkg, sat_tokens,
      wpool, bk, bv, bkv, front_feat, ffT,
      bev_xy, pos_w1, pos_b1, pos_h,
      plucker, plk_w1, plk_b1, plk_h,
      sat_xy, sxy_w1, sxy_b1, sxy_h);

  // L1 GEMMs (64x64 tiles, r5 layout)
  GP gpos {pos_h, wpool + OFF_POSW2, pos_b2, pos, 512, 512, 4096};
  GP gfeat{ffT, wpool + OFF_FAW, fa_b, feat_pre, 320, 512, 4096};
  GP gsat {wpool + OFF_SATT, wpool + OFF_SAW, sa_b, satf_pre, 768, 512, 1024};
  GP ggq1 {plk_h, wpool + OFF_PLKW2, plk_b2, plk2, 128, 128, 4096};
  GP ggk1 {sxy_h, wpool + OFF_SXYW2, sxy_b2, sxy2, 128, 128, 1024};
  k_gemm_L1<<<dim3(1312), b256, 0, stream>>>(gpos, gfeat, gsat, ggq1, ggk1);

  // LNs
  k_ln_all<<<dim3(2560), b256, 0, stream>>>(
      feat_pre, pos, fa_ln_g, fa_ln_b, qn_g, qn_b, q_embed,
      satf_pre, sa_ln_g, sa_ln_b, satf,
      plk2, sxy2, gqn_g, gqn_b, gkn_g, gkn_b, plk_ln, sgf);

  // L2 GEMMs
  GP gq  {q_embed, wpool + OFF_WQ, bq, q_lin, 512, 512, 4096};
  GP gkv {satf, wpool + OFF_WKV, bkv, kv_lin, 512, 1024, 1024};
  GP ggq2{plk_ln, wpool + OFF_WQG, bqg, qg_lin, 128, 128, 4096};
  GP ggk2{sgf, wpool + OFF_WKG, bkg, kg_lin, 128, 128, 1024};
  k_gemm_L2<<<dim3(928), b256, 0, stream>>>(gq, gkv, ggq2, ggk2);

  // prep (qk aug + vt)
  k_prep<<<dim3(10368), b256, 0, stream>>>(
      q_lin, qg_lin, bev_xy, Qaug, kv_lin, kg_lin, sat_xy, Kaug, kk2, VT);

  k_flash<<<dim3(NF / 64, 8, 2), b256, 0, stream>>>(Qaug, Kaug, VT, kk2, Opart, lbuf);
  k_combine<<<dim3(NF * MD / 4 / 256), b256, 0, stream>>>(Opart, lbuf, (float*)d_out);
}

// Round 8
// 79.758 us; speedup vs baseline: 1.3027x; 1.0910x over previous
//
#include <hip/hip_runtime.h>
#include <hip/hip_bf16.h>
#include <stdint.h>

// Problem constants
#define NF 4096
#define NS 1024
#define MD 512
#define HD 64
#define DA 96
#define GHID 128

#define L2E 1.44269504f          // log2(e)
#define S2L 1.6986436f           // sqrt(2*log2e)  (LAMBDA_GEO=1)
#define SMAX 12.0f               // static softmax offset

typedef unsigned short u16;
typedef __attribute__((ext_vector_type(8))) short bf8v;   // 8 bf16
typedef __attribute__((ext_vector_type(4))) float f4v;

__device__ __forceinline__ u16 f2bf(float f) {
  __hip_bfloat16 h = __float2bfloat16(f);
  return __builtin_bit_cast(u16, h);
}
__device__ __forceinline__ float bf2f(u16 u) {
  union { unsigned u; float f; } v; v.u = ((unsigned)u) << 16; return v.f;
}
__device__ __forceinline__ f4v mfma16(bf8v a, bf8v b, f4v c) {
  return __builtin_amdgcn_mfma_f32_16x16x32_bf16(a, b, c, 0, 0, 0);
}
__device__ __forceinline__ void gld16(const void* g, void* l) {
  __builtin_amdgcn_global_load_lds(
      (const __attribute__((address_space(1))) unsigned int*)g,
      (__attribute__((address_space(3))) unsigned int*)l, 16, 0, 0);
}

// weight pool offsets (bf16 elements)
#define OFF_POSW2 0
#define OFF_FAW   262144
#define OFF_SAW   425984
#define OFF_WQ    819200
#define OFF_WKV   1081344
#define OFF_PLKW2 1605632
#define OFF_SXYW2 1622016
#define OFF_WQG   1638400
#define OFF_WKG   1654784
#define OFF_SATT  1671168
#define TOTW      2457600

// epilogue modes
#define EPI_OUT  0
#define EPI_ROPE 1
#define EPI_VT   2
#define EPI_GEO  3

// ================= L0: convert + ffT + silus + aug pad/cross dims + kk2 =================
// blocks: [0,2401) convert, [2401,3041) ffT, [3041,13793) silu, [13793,13953) pad
__global__ __launch_bounds__(256) void k_l0(
    const float* __restrict__ s0, const float* __restrict__ s1,
    const float* __restrict__ s2, const float* __restrict__ s3,
    const float* __restrict__ s4, const float* __restrict__ s5,
    const float* __restrict__ s6, const float* __restrict__ s7,
    const float* __restrict__ s8, const float* __restrict__ s9,
    const float* __restrict__ s10, u16* __restrict__ pool,
    const float* __restrict__ bk, const float* __restrict__ bv,
    float* __restrict__ bkv,
    const float* __restrict__ ff, u16* __restrict__ ffT,
    const float* __restrict__ in0, const float* __restrict__ w0,
    const float* __restrict__ b0, u16* __restrict__ o0,
    const float* __restrict__ in1, const float* __restrict__ w1,
    const float* __restrict__ b1, u16* __restrict__ o1,
    const float* __restrict__ in2, const float* __restrict__ w2,
    const float* __restrict__ b2, u16* __restrict__ o2,
    u16* __restrict__ Qaug, u16* __restrict__ Kaug, float* __restrict__ kk2) {
  __shared__ u16 sT[32][72];
  int blk = blockIdx.x, t = threadIdx.x;
  if (blk < 2401) {
    int i4 = blk * 256 + t;
    if (i4 < TOTW / 4) {
      int idx = i4 * 4;
      const float* src; int off;
      if      (idx < OFF_FAW)   { src = s0;  off = OFF_POSW2; }
      else if (idx < OFF_SAW)   { src = s1;  off = OFF_FAW; }
      else if (idx < OFF_WQ)    { src = s2;  off = OFF_SAW; }
      else if (idx < OFF_WKV)   { src = s3;  off = OFF_WQ; }
      else if (idx < 1343488)   { src = s4;  off = OFF_WKV; }
      else if (idx < OFF_PLKW2) { src = s5;  off = 1343488; }
      else if (idx < OFF_SXYW2) { src = s6;  off = OFF_PLKW2; }
      else if (idx < OFF_WQG)   { src = s7;  off = OFF_SXYW2; }
      else if (idx < OFF_WKG)   { src = s8;  off = OFF_WQG; }
      else if (idx < OFF_SATT)  { src = s9;  off = OFF_WKG; }
      else                      { src = s10; off = OFF_SATT; }
      float4 v = *(const float4*)(src + (idx - off));
      ushort4 o;
      o.x = f2bf(v.x); o.y = f2bf(v.y); o.z = f2bf(v.z); o.w = f2bf(v.w);
      *(ushort4*)(pool + idx) = o;
    } else if (i4 < TOTW / 4 + 256) {
      int j = (i4 - TOTW / 4) * 4;
#pragma unroll
      for (int e = 0; e < 4; ++e) {
        int b = j + e;
        bkv[b] = (b < 512) ? bk[b] : bv[b - 512];
      }
    }
  } else if (blk < 3041) {
    int lb = blk - 2401;
    int n0 = (lb & 63) * 64, c0 = (lb >> 6) * 32;
    {
      int cr = t >> 3, nc = (t & 7) * 8;
      const float* src = ff + (size_t)(c0 + cr) * NF + n0 + nc;
      float4 v0 = *(const float4*)src, v1 = *(const float4*)(src + 4);
      bf8v p;
      p[0]=(short)f2bf(v0.x); p[1]=(short)f2bf(v0.y); p[2]=(short)f2bf(v0.z); p[3]=(short)f2bf(v0.w);
      p[4]=(short)f2bf(v1.x); p[5]=(short)f2bf(v1.y); p[6]=(short)f2bf(v1.z); p[7]=(short)f2bf(v1.w);
      *(bf8v*)&sT[cr][nc] = p;
    }
    __syncthreads();
    {
      int r = t >> 2, cc = (t & 3) * 8;
      bf8v p;
#pragma unroll
      for (int e = 0; e < 8; ++e) p[e] = (short)sT[cc + e][r];
      *(bf8v*)(ffT + (size_t)(n0 + r) * 320 + c0 + cc) = p;
    }
  } else if (blk < 13793) {
    int lb = blk - 3041;
    const float *in, *w, *b; u16* o; int mlog, K, idx;
    if (lb < 8192)       { in = in0; w = w0; b = b0; o = o0; mlog = 9; K = 2; idx = lb * 256 + t; }
    else if (lb < 10240) { in = in1; w = w1; b = b1; o = o1; mlog = 7; K = 6; idx = (lb - 8192) * 256 + t; }
    else                 { in = in2; w = w2; b = b2; o = o2; mlog = 7; K = 2; idx = (lb - 10240) * 256 + t; }
    int M = 1 << mlog;
    int n = idx >> mlog, m = idx & (M - 1);
    float acc = b[m];
    for (int k = 0; k < K; ++k) acc += in[n * K + k] * w[m * K + k];
    o[idx] = f2bf(acc / (1.f + __expf(-acc)));
  } else {
    // aug cross dims [80:96) + kk2 (depends only on inputs)
    int id = (blk - 13793) * 256 + t;       // 40960 total
    int side = id >= NF * 8;
    int lid = side ? id - NF * 8 : id;
    int n = lid >> 3, h = lid & 7;
    const float* xy = side ? in2 : in0;     // sat_xy : bev_xy
    u16* aug = side ? Kaug : Qaug;
    int nrows = side ? NS : NF;
    float x = xy[n * 2], y = xy[n * 2 + 1];
    bf8v p0, z;
#pragma unroll
    for (int e = 0; e < 8; ++e) { p0[e] = 0; z[e] = 0; }
    p0[0] = (short)f2bf(S2L * x);
    p0[1] = (short)f2bf(S2L * y);
    u16* dst = aug + ((size_t)h * nrows + n) * DA + 80;
    *(bf8v*)dst = p0;
    *(bf8v*)(dst + 8) = z;
    if (side && h == 0) kk2[n] = L2E * (x * x + y * y) + SMAX;
  }
}

// ================= bf16 MFMA GEMM body, 64x64 tile, BK=64, dbuf LDS, fused epilogues =================
__device__ __forceinline__ void gemm_body(const u16* __restrict__ A, const u16* __restrict__ W,
                                          const float* __restrict__ bias, u16* __restrict__ out,
                                          int m0, int n0, int N, int K,
                                          int mode, float scale, const float* __restrict__ xy,
                                          u16* __restrict__ aug, int nrows) {
  constexpr int MR = 2, NR = 2;        // per-wave 32x32
  __shared__ u16 sA[2][64 * 64];
  __shared__ u16 sB[2][64 * 64];
  const int tid = threadIdx.x, w = tid >> 6, lane = tid & 63;
  const int l16 = lane & 15, lh = lane >> 4;
  const int wr = w >> 1, wc = w & 1;

  f4v acc[MR][NR];
#pragma unroll
  for (int m = 0; m < MR; ++m)
#pragma unroll
    for (int j = 0; j < NR; ++j) acc[m][j] = (f4v){0.f, 0.f, 0.f, 0.f};

  auto stageA = [&](int buf, int k0) {
#pragma unroll
    for (int i = 0; i < 2; ++i) {
      int c = i * 256 + tid;
      int row = c >> 3, cp = c & 7;
      int sc_ = cp ^ (row & 7);
      gld16(A + (size_t)(m0 + row) * K + k0 + sc_ * 8, &sA[buf][c * 8]);
    }
  };
  auto stageB = [&](int buf, int k0) {
#pragma unroll
    for (int i = 0; i < 2; ++i) {
      int c = i * 256 + tid;
      int row = c >> 3, cp = c & 7;
      int sc_ = cp ^ (row & 7);
      gld16(W + (size_t)(n0 + row) * K + k0 + sc_ * 8, &sB[buf][c * 8]);
    }
  };

  stageA(0, 0); stageB(0, 0);
  __syncthreads();
  const int NK = K >> 6;
  for (int ks = 0; ks < NK; ++ks) {
    int nb = ks & 1;
    if (ks + 1 < NK) { stageA(nb ^ 1, (ks + 1) * 64); stageB(nb ^ 1, (ks + 1) * 64); }
#pragma unroll
    for (int kk = 0; kk < 2; ++kk) {
      bf8v af[MR], bfr[NR];
#pragma unroll
      for (int m = 0; m < MR; ++m) {
        int row = wr * 32 + m * 16 + l16;
        int cp = (kk * 4 + lh) ^ (row & 7);
        af[m] = *(const bf8v*)&sA[nb][row * 64 + cp * 8];
      }
#pragma unroll
      for (int j = 0; j < NR; ++j) {
        int row = wc * 32 + j * 16 + l16;
        int cp = (kk * 4 + lh) ^ (row & 7);
        bfr[j] = *(const bf8v*)&sB[nb][row * 64 + cp * 8];
      }
#pragma unroll
      for (int m = 0; m < MR; ++m)
#pragma unroll
        for (int j = 0; j < NR; ++j) acc[m][j] = mfma16(af[m], bfr[j], acc[m][j]);
    }
    __syncthreads();
  }

  if (mode == EPI_OUT) {
#pragma unroll
    for (int m = 0; m < MR; ++m) {
      int grow = m0 + wr * 32 + m * 16 + (lh << 2);
#pragma unroll
      for (int j = 0; j < NR; ++j) {
        int gcol = n0 + wc * 32 + j * 16 + l16;
        float bvs = bias ? bias[gcol] : 0.f;
#pragma unroll
        for (int r = 0; r < 4; ++r)
          out[(size_t)(grow + r) * N + gcol] = f2bf(acc[m][j][r] + bvs);
      }
    }
  } else if (mode == EPI_ROPE) {
    // main dims -> aug[0:64) with 2D rope on d<32 (wc==0 waves), scale folded
    float fr = __expf(-(float)(l16 & 7) * 1.1512925465f);   // 10000^(-(d&7)/8)
#pragma unroll
    for (int m = 0; m < MR; ++m) {
      int grow = m0 + wr * 32 + m * 16 + (lh << 2);
#pragma unroll
      for (int j = 0; j < NR; ++j) {
        int gcol = n0 + wc * 32 + j * 16 + l16;
        int h = gcol >> 6, d = gcol & 63;
        float bvs = bias[gcol];
#pragma unroll
        for (int r = 0; r < 4; ++r) {
          int n = grow + r;
          float val = acc[m][j][r] + bvs;
          float part = __shfl_xor(val, 8);
          float outv = val;
          if (wc == 0) {          // d < 32: rope (wave-uniform branch)
            float2 c2 = ((const float2*)xy)[n];
            float coord = j ? c2.y : c2.x;
            float sn, cs;
            __sincosf(coord * fr, &sn, &cs);
            outv = (l16 & 8) ? (part * sn + val * cs) : (val * cs - part * sn);
          }
          aug[((size_t)h * nrows + n) * DA + d] = f2bf(outv * scale);
        }
      }
    }
  } else if (mode == EPI_VT) {
    // V columns -> VT[h][d][n] (4 consecutive n per lane = ushort4)
#pragma unroll
    for (int m = 0; m < MR; ++m) {
      int grow = m0 + wr * 32 + m * 16 + (lh << 2);
#pragma unroll
      for (int j = 0; j < NR; ++j) {
        int gcol = n0 + wc * 32 + j * 16 + l16;
        int vcol = gcol - 512;
        int h = vcol >> 6, d = vcol & 63;
        float bvs = bias[gcol];
        ushort4 o;
        o.x = f2bf(acc[m][j][0] + bvs);
        o.y = f2bf(acc[m][j][1] + bvs);
        o.z = f2bf(acc[m][j][2] + bvs);
        o.w = f2bf(acc[m][j][3] + bvs);
        *(ushort4*)(aug + ((size_t)(h * 64 + d)) * NS + grow) = o;
      }
    }
  } else {
    // geo head -> aug[64:80), scale folded
#pragma unroll
    for (int m = 0; m < MR; ++m) {
      int grow = m0 + wr * 32 + m * 16 + (lh << 2);
#pragma unroll
      for (int j = 0; j < NR; ++j) {
        int gcol = n0 + wc * 32 + j * 16 + l16;
        int h = gcol >> 4, dg = gcol & 15;
        float bvs = bias[gcol];
#pragma unroll
        for (int r = 0; r < 4; ++r)
          aug[((size_t)h * nrows + grow + r) * DA + 64 + dg] = f2bf((acc[m][j][r] + bvs) * scale);
      }
    }
  }
}

struct GP { const u16* A; const u16* W; const float* bias; u16* out;
            int K; int N; int M; int mode; float scale; const float* xy;
            u16* aug; int nrows; };

__device__ __forceinline__ void gemm_dispatch(const GP& g, int blk) {
  int mt = g.M >> 6;
  int m0 = (blk % mt) * 64, n0 = (blk / mt) * 64;
  gemm_body(g.A, g.W, g.bias, g.out, m0, n0, g.N, g.K,
            g.mode, g.scale, g.xy, g.aug, g.nrows);
}

// L1: pos(512) feat(512) sat(128) geo1q(128) geo1k(32) = 1312 blocks
__global__ __launch_bounds__(256) void k_gemm_L1(GP a, GP b, GP c, GP d, GP e) {
  int blk = blockIdx.x;
  if (blk < 512)       gemm_dispatch(a, blk);
  else if (blk < 1024) gemm_dispatch(b, blk - 512);
  else if (blk < 1152) gemm_dispatch(c, blk - 1024);
  else if (blk < 1280) gemm_dispatch(d, blk - 1152);
  else                 gemm_dispatch(e, blk - 1280);
}
// L2: q(512) kv(256) geo2q(128) geo2k(32) = 928 blocks; fused prep epilogues
__global__ __launch_bounds__(256) void k_gemm_L2(GP a, GP b, GP c, GP d, u16* VTp) {
  int blk = blockIdx.x;
  if (blk < 512) {
    gemm_dispatch(a, blk);
  } else if (blk < 768) {
    int lb = blk - 512;
    int m0 = (lb & 15) * 64, n0 = (lb >> 4) * 64;
    if (n0 >= 512)
      gemm_body(b.A, b.W, b.bias, b.out, m0, n0, b.N, b.K, EPI_VT, 1.f, nullptr, VTp, NS);
    else
      gemm_body(b.A, b.W, b.bias, b.out, m0, n0, b.N, b.K, b.mode, b.scale, b.xy, b.aug, b.nrows);
  } else if (blk < 896) {
    gemm_dispatch(c, blk - 768);
  } else {
    gemm_dispatch(d, blk - 896);
  }
}

// ================= merged LayerNorms =================
// blocks: [0,1024) front chain, [1024,1280) sat D=512, [1280,2560) geo D=128
__global__ __launch_bounds__(256) void k_ln_all(
    const u16* __restrict__ feat_pre, const u16* __restrict__ pos,
    const float* __restrict__ fg, const float* __restrict__ fb,
    const float* __restrict__ qg, const float* __restrict__ qb2,
    u16* __restrict__ q_embed,
    const u16* __restrict__ satf_pre, const float* __restrict__ sg,
    const float* __restrict__ sb, u16* __restrict__ satf,
    const u16* __restrict__ ginq, const u16* __restrict__ gink,
    const float* __restrict__ ggq, const float* __restrict__ gbq,
    const float* __restrict__ ggk, const float* __restrict__ gbk,
    u16* __restrict__ goutq, u16* __restrict__ goutk) {
  int blk = blockIdx.x;
  int w = threadIdx.x >> 6, lane = threadIdx.x & 63;
  if (blk < 1024) {
    int row = blk * 4 + w;
    bf8v v = *(const bf8v*)(feat_pre + (size_t)row * 512 + lane * 8);
    float x[8];
#pragma unroll
    for (int e = 0; e < 8; ++e) x[e] = bf2f((u16)v[e]);
    float s = 0.f, q = 0.f;
#pragma unroll
    for (int e = 0; e < 8; ++e) { s += x[e]; q += x[e] * x[e]; }
#pragma unroll
    for (int mm = 1; mm < 64; mm <<= 1) { s += __shfl_xor(s, mm); q += __shfl_xor(q, mm); }
    float mean = s / 512.f, var = q / 512.f - mean * mean;
    float rstd = rsqrtf(var + 1e-5f);
    bf8v vp = *(const bf8v*)(pos + (size_t)row * 512 + lane * 8);
#pragma unroll
    for (int e = 0; e < 8; ++e)
      x[e] = (x[e] - mean) * rstd * fg[lane * 8 + e] + fb[lane * 8 + e] + bf2f((u16)vp[e]);
    s = 0.f; q = 0.f;
#pragma unroll
    for (int e = 0; e < 8; ++e) { s += x[e]; q += x[e] * x[e]; }
#pragma unroll
    for (int mm = 1; mm < 64; mm <<= 1) { s += __shfl_xor(s, mm); q += __shfl_xor(q, mm); }
    mean = s / 512.f; var = q / 512.f - mean * mean;
    rstd = rsqrtf(var + 1e-5f);
    bf8v ov;
#pragma unroll
    for (int e = 0; e < 8; ++e)
      ov[e] = (short)f2bf((x[e] - mean) * rstd * qg[lane * 8 + e] + qb2[lane * 8 + e]);
    *(bf8v*)(q_embed + (size_t)row * 512 + lane * 8) = ov;
  } else if (blk < 1280) {
    int row = (blk - 1024) * 4 + w;
    bf8v v = *(const bf8v*)(satf_pre + (size_t)row * 512 + lane * 8);
    float x[8];
#pragma unroll
    for (int e = 0; e < 8; ++e) x[e] = bf2f((u16)v[e]);
    float s = 0.f, q = 0.f;
#pragma unroll
    for (int e = 0; e < 8; ++e) { s += x[e]; q += x[e] * x[e]; }
#pragma unroll
    for (int mm = 1; mm < 64; mm <<= 1) { s += __shfl_xor(s, mm); q += __shfl_xor(q, mm); }
    float mean = s / 512.f, var = q / 512.f - mean * mean;
    float rstd = rsqrtf(var + 1e-5f);
    bf8v ov;
#pragma unroll
    for (int e = 0; e < 8; ++e)
      ov[e] = (short)f2bf((x[e] - mean) * rstd * sg[lane * 8 + e] + sb[lane * 8 + e]);
    *(bf8v*)(satf + (size_t)row * 512 + lane * 8) = ov;
  } else {
    int row = (blk - 1280) * 4 + w;
    const u16* in; const float *g, *b; u16* out;
    if (row < 4096) { in = ginq; g = ggq; b = gbq; out = goutq; }
    else { row -= 4096; in = gink; g = ggk; b = gbk; out = goutk; }
    uint32_t v = *(const uint32_t*)(in + (size_t)row * 128 + lane * 2);
    float x0 = bf2f((u16)(v & 0xffff)), x1 = bf2f((u16)(v >> 16));
    float s = x0 + x1, q = x0 * x0 + x1 * x1;
#pragma unroll
    for (int mm = 1; mm < 64; mm <<= 1) { s += __shfl_xor(s, mm); q += __shfl_xor(q, mm); }
    float mean = s / 128.f, var = q / 128.f - mean * mean;
    float rstd = rsqrtf(var + 1e-5f);
    u16 o0 = f2bf((x0 - mean) * rstd * g[lane * 2] + b[lane * 2]);
    u16 o1 = f2bf((x1 - mean) * rstd * g[lane * 2 + 1] + b[lane * 2 + 1]);
    *(uint32_t*)(out + (size_t)row * 128 + lane * 2) = (uint32_t)o0 | ((uint32_t)o1 << 16);
  }
}

// ================= fused flash attention: static-offset softmax, bf16 Opart =================
__global__ __launch_bounds__(256, 4) void k_flash(const u16* __restrict__ Qa,
                                                  const u16* __restrict__ Ka,
                                                  const u16* __restrict__ VT,
                                                  const float* __restrict__ kk2,
                                                  u16* __restrict__ Opart,
                                                  float* __restrict__ lbuf) {
  const int h = blockIdx.y, qb = blockIdx.x, sp = blockIdx.z;
  const int tid = threadIdx.x, w = tid >> 6, lane = tid & 63;
  const int l16 = lane & 15, lh = lane >> 4;
  __shared__ u16 sK[64][104];
  __shared__ u16 sV[64][72];
  __shared__ u16 sP[4][16][72];
  __shared__ float sKK[512];

  ((float2*)sKK)[tid] = ((const float2*)(kk2 + sp * 512))[tid];

  const int qrow = qb * 64 + w * 16 + l16;
  bf8v qf[3];
#pragma unroll
  for (int c = 0; c < 3; ++c)
    qf[c] = *(const bf8v*)(Qa + (size_t)(h * NF + qrow) * DA + c * 32 + lh * 8);

  bf8v ONES;
#pragma unroll
  for (int i = 0; i < 8; ++i) ONES[i] = (short)0x3F80;

  const int crow = qb * 64 + w * 16 + (lh << 2);
  float l_run[4] = {0.f, 0.f, 0.f, 0.f};
  f4v accO[4];
#pragma unroll
  for (int d = 0; d < 4; ++d) accO[d] = (f4v){0.f, 0.f, 0.f, 0.f};

  const int kt0 = sp * 8;
  bf8v kreg[3], vreg[2];
  auto sload = [&](int t8) {
    int kb = (kt0 + t8) * 64;
#pragma unroll
    for (int i = 0; i < 3; ++i) {
      int c = tid + i * 256; int r = c / 12, off = (c % 12) * 8;
      kreg[i] = *(const bf8v*)(Ka + ((size_t)(h * NS) + kb + r) * DA + off);
    }
#pragma unroll
    for (int i = 0; i < 2; ++i) {
      int c = tid + i * 256; int d = c >> 3, off = (c & 7) * 8;
      vreg[i] = *(const bf8v*)(VT + ((size_t)(h * HD) + d) * NS + kb + off);
    }
  };
  auto swrite = [&]() {
#pragma unroll
    for (int i = 0; i < 3; ++i) {
      int c = tid + i * 256; int r = c / 12, off = (c % 12) * 8;
      *(bf8v*)&sK[r][off] = kreg[i];
    }
#pragma unroll
    for (int i = 0; i < 2; ++i) {
      int c = tid + i * 256; int d = c >> 3, off = (c & 7) * 8;
      *(bf8v*)&sV[d][off] = vreg[i];
    }
  };

  sload(0); swrite();
  __syncthreads();
  for (int t8 = 0; t8 < 8; ++t8) {
    if (t8 < 7) sload(t8 + 1);
#pragma unroll
    for (int j = 0; j < 4; ++j) {
      f4v s4 = (f4v){0.f, 0.f, 0.f, 0.f};
#pragma unroll
      for (int c = 0; c < 3; ++c) {
        bf8v kf = *(const bf8v*)&sK[j * 16 + l16][c * 32 + lh * 8];
        s4 = mfma16(qf[c], kf, s4);
      }
      float ck = sKK[t8 * 64 + j * 16 + l16];
#pragma unroll
      for (int r = 0; r < 4; ++r) {
        float pv = exp2f(s4[r] - ck);
        sP[w][(lh << 2) + r][j * 16 + l16] = f2bf(pv);
      }
    }
    bf8v pf0 = *(const bf8v*)&sP[w][l16][lh * 8];
    bf8v pf1 = *(const bf8v*)&sP[w][l16][32 + lh * 8];
    f4v ls = (f4v){0.f, 0.f, 0.f, 0.f};
    ls = mfma16(pf0, ONES, ls);
    ls = mfma16(pf1, ONES, ls);
#pragma unroll
    for (int r = 0; r < 4; ++r) l_run[r] += ls[r];
#pragma unroll
    for (int c = 0; c < 2; ++c) {
      bf8v pf = (c == 0) ? pf0 : pf1;
#pragma unroll
      for (int d = 0; d < 4; ++d) {
        bf8v vf = *(const bf8v*)&sV[d * 16 + l16][c * 32 + lh * 8];
        accO[d] = mfma16(pf, vf, accO[d]);
      }
    }
    __syncthreads();
    if (t8 < 7) swrite();
    __syncthreads();
  }
  size_t obase = (size_t)(sp * 8 + h) * NF + crow;
#pragma unroll
  for (int d = 0; d < 4; ++d)
#pragma unroll
    for (int r = 0; r < 4; ++r)
      Opart[(obase + r) * 64 + d * 16 + l16] = f2bf(accO[d][r]);
  if (l16 == 0) {
#pragma unroll
    for (int r = 0; r < 4; ++r) lbuf[obase + r] = l_run[r];
  }
}

// ================= combine the 2 NS-splits (bf16 partials) =================
__global__ void k_combine(const u16* __restrict__ Opart, const float* __restrict__ lbuf,
                          float* __restrict__ out) {
  int i4 = blockIdx.x * 256 + threadIdx.x;
  int n = i4 >> 7;
  int c4 = i4 & 127, h = c4 >> 4, d4 = c4 & 15;
  float l = lbuf[(size_t)h * NF + n] + lbuf[(size_t)(8 + h) * NF + n];
  float rl = 1.f / l;
  ushort4 a = ((const ushort4*)(Opart + ((size_t)h * NF + n) * 64))[d4];
  ushort4 b = ((const ushort4*)(Opart + ((size_t)(8 + h) * NF + n) * 64))[d4];
  float4 r;
  r.x = (bf2f(a.x) + bf2f(b.x)) * rl;
  r.y = (bf2f(a.y) + bf2f(b.y)) * rl;
  r.z = (bf2f(a.z) + bf2f(b.z)) * rl;
  r.w = (bf2f(a.w) + bf2f(b.w)) * rl;
  ((float4*)out)[i4] = r;
}

extern "C" void kernel_launch(void* const* d_in, const int* in_sizes, int n_in,
                              void* d_out, int out_size, void* d_ws, size_t ws_size,
                              hipStream_t stream) {
  (void)in_sizes; (void)n_in; (void)out_size; (void)ws_size;
  const float* front_feat = (const float*)d_in[0];
  const float* bev_xy     = (const float*)d_in[1];
  const float* sat_tokens = (const float*)d_in[2];
  const float* sat_xy     = (const float*)d_in[3];
  const float* plucker    = (const float*)d_in[4];
  const float* pos_w1 = (const float*)d_in[5];
  const float* pos_b1 = (const float*)d_in[6];
  const float* pos_w2 = (const float*)d_in[7];
  const float* pos_b2 = (const float*)d_in[8];
  const float* fa_w   = (const float*)d_in[9];
  const float* fa_b   = (const float*)d_in[10];
  const float* fa_ln_g = (const float*)d_in[11];
  const float* fa_ln_b = (const float*)d_in[12];
  const float* qn_g   = (const float*)d_in[13];
  const float* qn_b   = (const float*)d_in[14];
  const float* sa_w   = (const float*)d_in[15];
  const float* sa_b   = (const float*)d_in[16];
  const float* sa_ln_g = (const float*)d_in[17];
  const float* sa_ln_b = (const float*)d_in[18];
  const float* wq = (const float*)d_in[19];
  const float* bq = (const float*)d_in[20];
  const float* wk = (const float*)d_in[21];
  const float* bk = (const float*)d_in[22];
  const float* wv = (const float*)d_in[23];
  const float* bv = (const float*)d_in[24];
  const float* plk_w1 = (const float*)d_in[25];
  const float* plk_b1 = (const float*)d_in[26];
  const float* plk_w2 = (const float*)d_in[27];
  const float* plk_b2 = (const float*)d_in[28];
  const float* sxy_w1 = (const float*)d_in[29];
  const float* sxy_b1 = (const float*)d_in[30];
  const float* sxy_w2 = (const float*)d_in[31];
  const float* sxy_b2 = (const float*)d_in[32];
  const float* gqn_g = (const float*)d_in[33];
  const float* gqn_b = (const float*)d_in[34];
  const float* gkn_g = (const float*)d_in[35];
  const float* gkn_b = (const float*)d_in[36];
  const float* wqg = (const float*)d_in[37];
  const float* bqg = (const float*)d_in[38];
  const float* wkg = (const float*)d_in[39];
  const float* bkg = (const float*)d_in[40];

  char* ws = (char*)d_ws;
  size_t off = 0;
  auto alloc = [&](size_t bytes) {
    size_t r = off;
    off += (bytes + 255) & ~(size_t)255;
    return r;
  };
  u16*   wpool   = (u16*)(ws + alloc((size_t)TOTW * 2));
  float* bkv     = (float*)(ws + alloc(1024 * 4));
  u16*   ffT     = (u16*)(ws + alloc((size_t)NF * 320 * 2));
  u16*   pos_h   = (u16*)(ws + alloc((size_t)NF * MD * 2));
  u16*   plk_h   = (u16*)(ws + alloc((size_t)NF * GHID * 2));
  u16*   sxy_h   = (u16*)(ws + alloc((size_t)NS * GHID * 2));
  u16*   pos     = (u16*)(ws + alloc((size_t)NF * MD * 2));
  u16*   feat_pre= (u16*)(ws + alloc((size_t)NF * MD * 2));
  u16*   satf_pre= (u16*)(ws + alloc((size_t)NS * MD * 2));
  u16*   satf    = (u16*)(ws + alloc((size_t)NS * MD * 2));
  u16*   q_embed = (u16*)(ws + alloc((size_t)NF * MD * 2));
  u16*   plk2    = (u16*)(ws + alloc((size_t)NF * GHID * 2));
  u16*   sxy2    = (u16*)(ws + alloc((size_t)NS * GHID * 2));
  u16*   Qaug    = (u16*)(ws + alloc((size_t)8 * NF * DA * 2));
  u16*   Kaug    = (u16*)(ws + alloc((size_t)8 * NS * DA * 2));
  u16*   VT      = (u16*)(ws + alloc((size_t)8 * HD * NS * 2));
  float* kk2     = (float*)(ws + alloc((size_t)NS * 4));
  u16*   Opart   = (u16*)(ws + alloc((size_t)2 * 8 * NF * 64 * 2));
  float* lbuf    = (float*)(ws + alloc((size_t)2 * 8 * NF * 4));
  // aliases (producer dead before alias written)
  u16* plk_ln = plk_h;
  u16* sgf    = sxy_h;

  dim3 b256(256);
  // L0: convert + ffT + silus + aug pad/kk2
  k_l0<<<dim3(13953), b256, 0, stream>>>(
      pos_w2, fa_w, sa_w, wq, wk, wv, plk_w2, sxy_w2, wqg, wkg, sat_tokens,
      wpool, bk, bv, bkv, front_feat, ffT,
      bev_xy, pos_w1, pos_b1, pos_h,
      plucker, plk_w1, plk_b1, plk_h,
      sat_xy, sxy_w1, sxy_b1, sxy_h,
      Qaug, Kaug, kk2);

  // L1 GEMMs (plain epilogues)
  GP gpos {pos_h, wpool + OFF_POSW2, pos_b2, pos, 512, 512, 4096, EPI_OUT, 0.f, nullptr, nullptr, 0};
  GP gfeat{ffT, wpool + OFF_FAW, fa_b, feat_pre, 320, 512, 4096, EPI_OUT, 0.f, nullptr, nullptr, 0};
  GP gsat {wpool + OFF_SATT, wpool + OFF_SAW, sa_b, satf_pre, 768, 512, 1024, EPI_OUT, 0.f, nullptr, nullptr, 0};
  GP ggq1 {plk_h, wpool + OFF_PLKW2, plk_b2, plk2, 128, 128, 4096, EPI_OUT, 0.f, nullptr, nullptr, 0};
  GP ggk1 {sxy_h, wpool + OFF_SXYW2, sxy_b2, sxy2, 128, 128, 1024, EPI_OUT, 0.f, nullptr, nullptr, 0};
  k_gemm_L1<<<dim3(1312), b256, 0, stream>>>(gpos, gfeat, gsat, ggq1, ggk1);

  // LNs
  k_ln_all<<<dim3(2560), b256, 0, stream>>>(
      feat_pre, pos, fa_ln_g, fa_ln_b, qn_g, qn_b, q_embed,
      satf_pre, sa_ln_g, sa_ln_b, satf,
      plk2, sxy2, gqn_g, gqn_b, gkn_g, gkn_b, plk_ln, sgf);

  // L2 GEMMs with fused rope/VT/geo epilogues (no prep pass)
  GP gq  {q_embed, wpool + OFF_WQ, bq, nullptr, 512, 512, 4096, EPI_ROPE, 0.125f * L2E, bev_xy, Qaug, NF};
  GP gkv {satf, wpool + OFF_WKV, bkv, nullptr, 512, 1024, 1024, EPI_ROPE, 1.f, sat_xy, Kaug, NS};
  GP ggq2{plk_ln, wpool + OFF_WQG, bqg, nullptr, 128, 128, 4096, EPI_GEO, 0.25f * L2E, nullptr, Qaug, NF};
  GP ggk2{sgf, wpool + OFF_WKG, bkg, nullptr, 128, 128, 1024, EPI_GEO, 1.f, nullptr, Kaug, NS};
  k_gemm_L2<<<dim3(928), b256, 0, stream>>>(gq, gkv, ggq2, ggk2, VT);

  k_flash<<<dim3(NF / 64, 8, 2), b256, 0, stream>>>(Qaug, Kaug, VT, kk2, Opart, lbuf);
  k_combine<<<dim3(NF * MD / 4 / 256), b256, 0, stream>>>(Opart, lbuf, (float*)d_out);
}

// Round 9
// 79.250 us; speedup vs baseline: 1.3110x; 1.0064x over previous
//
#include <hip/hip_runtime.h>
#include <hip/hip_bf16.h>
#include <stdint.h>

// Problem constants
#define NF 4096
#define NS 1024
#define MD 512
#define HD 64
#define DA 96
#define GHID 128

#define L2E 1.44269504f          // log2(e)
#define S2L 1.6986436f           // sqrt(2*log2e)  (LAMBDA_GEO=1)
#define SMAX 12.0f               // static softmax offset

typedef unsigned short u16;
typedef __attribute__((ext_vector_type(8))) short bf8v;   // 8 bf16
typedef __attribute__((ext_vector_type(4))) float f4v;

__device__ __forceinline__ u16 f2bf(float f) {
  __hip_bfloat16 h = __float2bfloat16(f);
  return __builtin_bit_cast(u16, h);
}
__device__ __forceinline__ float bf2f(u16 u) {
  union { unsigned u; float f; } v; v.u = ((unsigned)u) << 16; return v.f;
}
__device__ __forceinline__ f4v mfma16(bf8v a, bf8v b, f4v c) {
  return __builtin_amdgcn_mfma_f32_16x16x32_bf16(a, b, c, 0, 0, 0);
}
__device__ __forceinline__ void gld16(const void* g, void* l) {
  __builtin_amdgcn_global_load_lds(
      (const __attribute__((address_space(1))) unsigned int*)g,
      (__attribute__((address_space(3))) unsigned int*)l, 16, 0, 0);
}

// weight pool offsets (bf16 elements)
#define OFF_POSW2 0
#define OFF_FAW   262144
#define OFF_SAW   425984
#define OFF_WQ    819200
#define OFF_WKV   1081344
#define OFF_PLKW2 1605632
#define OFF_SXYW2 1622016
#define OFF_WQG   1638400
#define OFF_WKG   1654784
#define OFF_SATT  1671168
#define TOTW      2457600

// epilogue modes
#define EPI_OUT  0
#define EPI_ROPE 1
#define EPI_VT   2
#define EPI_GEO  3

// ================= L0: convert + ffT + silus + aug pad/cross dims + kk2 =================
// blocks: [0,2401) convert, [2401,3041) ffT, [3041,13793) silu, [13793,13953) pad
__global__ __launch_bounds__(256) void k_l0(
    const float* __restrict__ s0, const float* __restrict__ s1,
    const float* __restrict__ s2, const float* __restrict__ s3,
    const float* __restrict__ s4, const float* __restrict__ s5,
    const float* __restrict__ s6, const float* __restrict__ s7,
    const float* __restrict__ s8, const float* __restrict__ s9,
    const float* __restrict__ s10, u16* __restrict__ pool,
    const float* __restrict__ bk, const float* __restrict__ bv,
    float* __restrict__ bkv,
    const float* __restrict__ ff, u16* __restrict__ ffT,
    const float* __restrict__ in0, const float* __restrict__ w0,
    const float* __restrict__ b0, u16* __restrict__ o0,
    const float* __restrict__ in1, const float* __restrict__ w1,
    const float* __restrict__ b1, u16* __restrict__ o1,
    const float* __restrict__ in2, const float* __restrict__ w2,
    const float* __restrict__ b2, u16* __restrict__ o2,
    u16* __restrict__ Qaug, u16* __restrict__ Kaug, float* __restrict__ kk2) {
  __shared__ u16 sT[32][72];
  int blk = blockIdx.x, t = threadIdx.x;
  if (blk < 2401) {
    int i4 = blk * 256 + t;
    if (i4 < TOTW / 4) {
      int idx = i4 * 4;
      const float* src; int off;
      if      (idx < OFF_FAW)   { src = s0;  off = OFF_POSW2; }
      else if (idx < OFF_SAW)   { src = s1;  off = OFF_FAW; }
      else if (idx < OFF_WQ)    { src = s2;  off = OFF_SAW; }
      else if (idx < OFF_WKV)   { src = s3;  off = OFF_WQ; }
      else if (idx < 1343488)   { src = s4;  off = OFF_WKV; }
      else if (idx < OFF_PLKW2) { src = s5;  off = 1343488; }
      else if (idx < OFF_SXYW2) { src = s6;  off = OFF_PLKW2; }
      else if (idx < OFF_WQG)   { src = s7;  off = OFF_SXYW2; }
      else if (idx < OFF_WKG)   { src = s8;  off = OFF_WQG; }
      else if (idx < OFF_SATT)  { src = s9;  off = OFF_WKG; }
      else                      { src = s10; off = OFF_SATT; }
      float4 v = *(const float4*)(src + (idx - off));
      ushort4 o;
      o.x = f2bf(v.x); o.y = f2bf(v.y); o.z = f2bf(v.z); o.w = f2bf(v.w);
      *(ushort4*)(pool + idx) = o;
    } else if (i4 < TOTW / 4 + 256) {
      int j = (i4 - TOTW / 4) * 4;
#pragma unroll
      for (int e = 0; e < 4; ++e) {
        int b = j + e;
        bkv[b] = (b < 512) ? bk[b] : bv[b - 512];
      }
    }
  } else if (blk < 3041) {
    int lb = blk - 2401;
    int n0 = (lb & 63) * 64, c0 = (lb >> 6) * 32;
    {
      int cr = t >> 3, nc = (t & 7) * 8;
      const float* src = ff + (size_t)(c0 + cr) * NF + n0 + nc;
      float4 v0 = *(const float4*)src, v1 = *(const float4*)(src + 4);
      bf8v p;
      p[0]=(short)f2bf(v0.x); p[1]=(short)f2bf(v0.y); p[2]=(short)f2bf(v0.z); p[3]=(short)f2bf(v0.w);
      p[4]=(short)f2bf(v1.x); p[5]=(short)f2bf(v1.y); p[6]=(short)f2bf(v1.z); p[7]=(short)f2bf(v1.w);
      *(bf8v*)&sT[cr][nc] = p;
    }
    __syncthreads();
    {
      int r = t >> 2, cc = (t & 3) * 8;
      bf8v p;
#pragma unroll
      for (int e = 0; e < 8; ++e) p[e] = (short)sT[cc + e][r];
      *(bf8v*)(ffT + (size_t)(n0 + r) * 320 + c0 + cc) = p;
    }
  } else if (blk < 13793) {
    int lb = blk - 3041;
    const float *in, *w, *b; u16* o; int mlog, K, idx;
    if (lb < 8192)       { in = in0; w = w0; b = b0; o = o0; mlog = 9; K = 2; idx = lb * 256 + t; }
    else if (lb < 10240) { in = in1; w = w1; b = b1; o = o1; mlog = 7; K = 6; idx = (lb - 8192) * 256 + t; }
    else                 { in = in2; w = w2; b = b2; o = o2; mlog = 7; K = 2; idx = (lb - 10240) * 256 + t; }
    int M = 1 << mlog;
    int n = idx >> mlog, m = idx & (M - 1);
    float acc = b[m];
    for (int k = 0; k < K; ++k) acc += in[n * K + k] * w[m * K + k];
    o[idx] = f2bf(acc / (1.f + __expf(-acc)));
  } else {
    // aug cross dims [80:96) + kk2 (depends only on inputs)
    int id = (blk - 13793) * 256 + t;       // 40960 total
    int side = id >= NF * 8;
    int lid = side ? id - NF * 8 : id;
    int n = lid >> 3, h = lid & 7;
    const float* xy = side ? in2 : in0;     // sat_xy : bev_xy
    u16* aug = side ? Kaug : Qaug;
    int nrows = side ? NS : NF;
    float x = xy[n * 2], y = xy[n * 2 + 1];
    bf8v p0, z;
#pragma unroll
    for (int e = 0; e < 8; ++e) { p0[e] = 0; z[e] = 0; }
    p0[0] = (short)f2bf(S2L * x);
    p0[1] = (short)f2bf(S2L * y);
    u16* dst = aug + ((size_t)h * nrows + n) * DA + 80;
    *(bf8v*)dst = p0;
    *(bf8v*)(dst + 8) = z;
    if (side && h == 0) kk2[n] = L2E * (x * x + y * y) + SMAX;
  }
}

// ================= 128x64-tile GEMM body (plain epilogue only) — for L1 =================
__device__ __forceinline__ void gemm_body128(const u16* __restrict__ A, const u16* __restrict__ W,
                                             const float* __restrict__ bias, u16* __restrict__ out,
                                             int m0, int n0, int N, int K) {
  __shared__ u16 sA[2][128 * 64];
  __shared__ u16 sB[2][64 * 64];
  const int tid = threadIdx.x, w = tid >> 6, lane = tid & 63;
  const int l16 = lane & 15, lh = lane >> 4;

  f4v acc[2][4];
#pragma unroll
  for (int m = 0; m < 2; ++m)
#pragma unroll
    for (int j = 0; j < 4; ++j) acc[m][j] = (f4v){0.f, 0.f, 0.f, 0.f};

  auto stageA = [&](int buf, int k0) {
#pragma unroll
    for (int i = 0; i < 4; ++i) {
      int c = i * 256 + tid;
      int row = c >> 3, cp = c & 7;
      int sc_ = cp ^ (row & 7);
      gld16(A + (size_t)(m0 + row) * K + k0 + sc_ * 8, &sA[buf][c * 8]);
    }
  };
  auto stageB = [&](int buf, int k0) {
#pragma unroll
    for (int i = 0; i < 2; ++i) {
      int c = i * 256 + tid;
      int row = c >> 3, cp = c & 7;
      int sc_ = cp ^ (row & 7);
      gld16(W + (size_t)(n0 + row) * K + k0 + sc_ * 8, &sB[buf][c * 8]);
    }
  };

  stageA(0, 0); stageB(0, 0);
  __syncthreads();
  const int NK = K >> 6;
  for (int ks = 0; ks < NK; ++ks) {
    int nb = ks & 1;
    if (ks + 1 < NK) { stageA(nb ^ 1, (ks + 1) * 64); stageB(nb ^ 1, (ks + 1) * 64); }
#pragma unroll
    for (int kk = 0; kk < 2; ++kk) {
      bf8v af[2], bfr[4];
#pragma unroll
      for (int m = 0; m < 2; ++m) {
        int row = w * 32 + m * 16 + l16;
        int cp = (kk * 4 + lh) ^ (row & 7);
        af[m] = *(const bf8v*)&sA[nb][row * 64 + cp * 8];
      }
#pragma unroll
      for (int j = 0; j < 4; ++j) {
        int row = j * 16 + l16;
        int cp = (kk * 4 + lh) ^ (row & 7);
        bfr[j] = *(const bf8v*)&sB[nb][row * 64 + cp * 8];
      }
#pragma unroll
      for (int m = 0; m < 2; ++m)
#pragma unroll
        for (int j = 0; j < 4; ++j) acc[m][j] = mfma16(af[m], bfr[j], acc[m][j]);
    }
    __syncthreads();
  }
#pragma unroll
  for (int m = 0; m < 2; ++m) {
    int grow = m0 + w * 32 + m * 16 + (lh << 2);
#pragma unroll
    for (int j = 0; j < 4; ++j) {
      int gcol = n0 + j * 16 + l16;
      float bvs = bias ? bias[gcol] : 0.f;
#pragma unroll
      for (int r = 0; r < 4; ++r)
        out[(size_t)(grow + r) * N + gcol] = f2bf(acc[m][j][r] + bvs);
    }
  }
}

// ================= 64x64-tile GEMM body, fused epilogues — for L2 (r8 version) =================
__device__ __forceinline__ void gemm_body(const u16* __restrict__ A, const u16* __restrict__ W,
                                          const float* __restrict__ bias, u16* __restrict__ out,
                                          int m0, int n0, int N, int K,
                                          int mode, float scale, const float* __restrict__ xy,
                                          u16* __restrict__ aug, int nrows) {
  constexpr int MR = 2, NR = 2;        // per-wave 32x32
  __shared__ u16 sA[2][64 * 64];
  __shared__ u16 sB[2][64 * 64];
  const int tid = threadIdx.x, w = tid >> 6, lane = tid & 63;
  const int l16 = lane & 15, lh = lane >> 4;
  const int wr = w >> 1, wc = w & 1;

  f4v acc[MR][NR];
#pragma unroll
  for (int m = 0; m < MR; ++m)
#pragma unroll
    for (int j = 0; j < NR; ++j) acc[m][j] = (f4v){0.f, 0.f, 0.f, 0.f};

  auto stageA = [&](int buf, int k0) {
#pragma unroll
    for (int i = 0; i < 2; ++i) {
      int c = i * 256 + tid;
      int row = c >> 3, cp = c & 7;
      int sc_ = cp ^ (row & 7);
      gld16(A + (size_t)(m0 + row) * K + k0 + sc_ * 8, &sA[buf][c * 8]);
    }
  };
  auto stageB = [&](int buf, int k0) {
#pragma unroll
    for (int i = 0; i < 2; ++i) {
      int c = i * 256 + tid;
      int row = c >> 3, cp = c & 7;
      int sc_ = cp ^ (row & 7);
      gld16(W + (size_t)(n0 + row) * K + k0 + sc_ * 8, &sB[buf][c * 8]);
    }
  };

  stageA(0, 0); stageB(0, 0);
  __syncthreads();
  const int NK = K >> 6;
  for (int ks = 0; ks < NK; ++ks) {
    int nb = ks & 1;
    if (ks + 1 < NK) { stageA(nb ^ 1, (ks + 1) * 64); stageB(nb ^ 1, (ks + 1) * 64); }
#pragma unroll
    for (int kk = 0; kk < 2; ++kk) {
      bf8v af[MR], bfr[NR];
#pragma unroll
      for (int m = 0; m < MR; ++m) {
        int row = wr * 32 + m * 16 + l16;
        int cp = (kk * 4 + lh) ^ (row & 7);
        af[m] = *(const bf8v*)&sA[nb][row * 64 + cp * 8];
      }
#pragma unroll
      for (int j = 0; j < NR; ++j) {
        int row = wc * 32 + j * 16 + l16;
        int cp = (kk * 4 + lh) ^ (row & 7);
        bfr[j] = *(const bf8v*)&sB[nb][row * 64 + cp * 8];
      }
#pragma unroll
      for (int m = 0; m < MR; ++m)
#pragma unroll
        for (int j = 0; j < NR; ++j) acc[m][j] = mfma16(af[m], bfr[j], acc[m][j]);
    }
    __syncthreads();
  }

  if (mode == EPI_OUT) {
#pragma unroll
    for (int m = 0; m < MR; ++m) {
      int grow = m0 + wr * 32 + m * 16 + (lh << 2);
#pragma unroll
      for (int j = 0; j < NR; ++j) {
        int gcol = n0 + wc * 32 + j * 16 + l16;
        float bvs = bias ? bias[gcol] : 0.f;
#pragma unroll
        for (int r = 0; r < 4; ++r)
          out[(size_t)(grow + r) * N + gcol] = f2bf(acc[m][j][r] + bvs);
      }
    }
  } else if (mode == EPI_ROPE) {
    // main dims -> aug[0:64) with 2D rope on d<32 (wc==0 waves), scale folded
    float fr = __expf(-(float)(l16 & 7) * 1.1512925465f);   // 10000^(-(d&7)/8)
#pragma unroll
    for (int m = 0; m < MR; ++m) {
      int grow = m0 + wr * 32 + m * 16 + (lh << 2);
#pragma unroll
      for (int j = 0; j < NR; ++j) {
        int gcol = n0 + wc * 32 + j * 16 + l16;
        int h = gcol >> 6, d = gcol & 63;
        float bvs = bias[gcol];
#pragma unroll
        for (int r = 0; r < 4; ++r) {
          int n = grow + r;
          float val = acc[m][j][r] + bvs;
          float part = __shfl_xor(val, 8);
          float outv = val;
          if (wc == 0) {          // d < 32: rope (wave-uniform branch)
            float2 c2 = ((const float2*)xy)[n];
            float coord = j ? c2.y : c2.x;
            float sn, cs;
            __sincosf(coord * fr, &sn, &cs);
            outv = (l16 & 8) ? (part * sn + val * cs) : (val * cs - part * sn);
          }
          aug[((size_t)h * nrows + n) * DA + d] = f2bf(outv * scale);
        }
      }
    }
  } else if (mode == EPI_VT) {
    // V columns -> VT[h][d][n] (4 consecutive n per lane = ushort4)
#pragma unroll
    for (int m = 0; m < MR; ++m) {
      int grow = m0 + wr * 32 + m * 16 + (lh << 2);
#pragma unroll
      for (int j = 0; j < NR; ++j) {
        int gcol = n0 + wc * 32 + j * 16 + l16;
        int vcol = gcol - 512;
        int h = vcol >> 6, d = vcol & 63;
        float bvs = bias[gcol];
        ushort4 o;
        o.x = f2bf(acc[m][j][0] + bvs);
        o.y = f2bf(acc[m][j][1] + bvs);
        o.z = f2bf(acc[m][j][2] + bvs);
        o.w = f2bf(acc[m][j][3] + bvs);
        *(ushort4*)(aug + ((size_t)(h * 64 + d)) * NS + grow) = o;
      }
    }
  } else {
    // geo head -> aug[64:80), scale folded
#pragma unroll
    for (int m = 0; m < MR; ++m) {
      int grow = m0 + wr * 32 + m * 16 + (lh << 2);
#pragma unroll
      for (int j = 0; j < NR; ++j) {
        int gcol = n0 + wc * 32 + j * 16 + l16;
        int h = gcol >> 4, dg = gcol & 15;
        float bvs = bias[gcol];
#pragma unroll
        for (int r = 0; r < 4; ++r)
          aug[((size_t)h * nrows + grow + r) * DA + 64 + dg] = f2bf((acc[m][j][r] + bvs) * scale);
      }
    }
  }
}

struct GP { const u16* A; const u16* W; const float* bias; u16* out;
            int K; int N; int M; int mode; float scale; const float* xy;
            u16* aug; int nrows; };

__device__ __forceinline__ void gemm_dispatch128(const GP& g, int blk) {
  int mt = g.M >> 7;
  int m0 = (blk % mt) * 128, n0 = (blk / mt) * 64;
  gemm_body128(g.A, g.W, g.bias, g.out, m0, n0, g.N, g.K);
}
__device__ __forceinline__ void gemm_dispatch(const GP& g, int blk) {
  int mt = g.M >> 6;
  int m0 = (blk % mt) * 64, n0 = (blk / mt) * 64;
  gemm_body(g.A, g.W, g.bias, g.out, m0, n0, g.N, g.K,
            g.mode, g.scale, g.xy, g.aug, g.nrows);
}

// L1 (128x64 tiles): pos(256) feat(256) sat(64) geo1q(64) geo1k(16) = 656 blocks
__global__ __launch_bounds__(256) void k_gemm_L1(GP a, GP b, GP c, GP d, GP e) {
  int blk = blockIdx.x;
  if (blk < 256)       gemm_dispatch128(a, blk);
  else if (blk < 512)  gemm_dispatch128(b, blk - 256);
  else if (blk < 576)  gemm_dispatch128(c, blk - 512);
  else if (blk < 640)  gemm_dispatch128(d, blk - 576);
  else                 gemm_dispatch128(e, blk - 640);
}
// L2 (64x64 tiles): q(512) kv(256) geo2q(128) geo2k(32) = 928 blocks; fused prep epilogues
__global__ __launch_bounds__(256) void k_gemm_L2(GP a, GP b, GP c, GP d, u16* VTp) {
  int blk = blockIdx.x;
  if (blk < 512) {
    gemm_dispatch(a, blk);
  } else if (blk < 768) {
    int lb = blk - 512;
    int m0 = (lb & 15) * 64, n0 = (lb >> 4) * 64;
    if (n0 >= 512)
      gemm_body(b.A, b.W, b.bias, b.out, m0, n0, b.N, b.K, EPI_VT, 1.f, nullptr, VTp, NS);
    else
      gemm_body(b.A, b.W, b.bias, b.out, m0, n0, b.N, b.K, b.mode, b.scale, b.xy, b.aug, b.nrows);
  } else if (blk < 896) {
    gemm_dispatch(c, blk - 768);
  } else {
    gemm_dispatch(d, blk - 896);
  }
}

// ================= merged LayerNorms =================
// blocks: [0,1024) front chain, [1024,1280) sat D=512, [1280,2560) geo D=128
__global__ __launch_bounds__(256) void k_ln_all(
    const u16* __restrict__ feat_pre, const u16* __restrict__ pos,
    const float* __restrict__ fg, const float* __restrict__ fb,
    const float* __restrict__ qg, const float* __restrict__ qb2,
    u16* __restrict__ q_embed,
    const u16* __restrict__ satf_pre, const float* __restrict__ sg,
    const float* __restrict__ sb, u16* __restrict__ satf,
    const u16* __restrict__ ginq, const u16* __restrict__ gink,
    const float* __restrict__ ggq, const float* __restrict__ gbq,
    const float* __restrict__ ggk, const float* __restrict__ gbk,
    u16* __restrict__ goutq, u16* __restrict__ goutk) {
  int blk = blockIdx.x;
  int w = threadIdx.x >> 6, lane = threadIdx.x & 63;
  if (blk < 1024) {
    int row = blk * 4 + w;
    bf8v v = *(const bf8v*)(feat_pre + (size_t)row * 512 + lane * 8);
    float x[8];
#pragma unroll
    for (int e = 0; e < 8; ++e) x[e] = bf2f((u16)v[e]);
    float s = 0.f, q = 0.f;
#pragma unroll
    for (int e = 0; e < 8; ++e) { s += x[e]; q += x[e] * x[e]; }
#pragma unroll
    for (int mm = 1; mm < 64; mm <<= 1) { s += __shfl_xor(s, mm); q += __shfl_xor(q, mm); }
    float mean = s / 512.f, var = q / 512.f - mean * mean;
    float rstd = rsqrtf(var + 1e-5f);
    bf8v vp = *(const bf8v*)(pos + (size_t)row * 512 + lane * 8);
#pragma unroll
    for (int e = 0; e < 8; ++e)
      x[e] = (x[e] - mean) * rstd * fg[lane * 8 + e] + fb[lane * 8 + e] + bf2f((u16)vp[e]);
    s = 0.f; q = 0.f;
#pragma unroll
    for (int e = 0; e < 8; ++e) { s += x[e]; q += x[e] * x[e]; }
#pragma unroll
    for (int mm = 1; mm < 64; mm <<= 1) { s += __shfl_xor(s, mm); q += __shfl_xor(q, mm); }
    mean = s / 512.f; var = q / 512.f - mean * mean;
    rstd = rsqrtf(var + 1e-5f);
    bf8v ov;
#pragma unroll
    for (int e = 0; e < 8; ++e)
      ov[e] = (short)f2bf((x[e] - mean) * rstd * qg[lane * 8 + e] + qb2[lane * 8 + e]);
    *(bf8v*)(q_embed + (size_t)row * 512 + lane * 8) = ov;
  } else if (blk < 1280) {
    int row = (blk - 1024) * 4 + w;
    bf8v v = *(const bf8v*)(satf_pre + (size_t)row * 512 + lane * 8);
    float x[8];
#pragma unroll
    for (int e = 0; e < 8; ++e) x[e] = bf2f((u16)v[e]);
    float s = 0.f, q = 0.f;
#pragma unroll
    for (int e = 0; e < 8; ++e) { s += x[e]; q += x[e] * x[e]; }
#pragma unroll
    for (int mm = 1; mm < 64; mm <<= 1) { s += __shfl_xor(s, mm); q += __shfl_xor(q, mm); }
    float mean = s / 512.f, var = q / 512.f - mean * mean;
    float rstd = rsqrtf(var + 1e-5f);
    bf8v ov;
#pragma unroll
    for (int e = 0; e < 8; ++e)
      ov[e] = (short)f2bf((x[e] - mean) * rstd * sg[lane * 8 + e] + sb[lane * 8 + e]);
    *(bf8v*)(satf + (size_t)row * 512 + lane * 8) = ov;
  } else {
    int row = (blk - 1280) * 4 + w;
    const u16* in; const float *g, *b; u16* out;
    if (row < 4096) { in = ginq; g = ggq; b = gbq; out = goutq; }
    else { row -= 4096; in = gink; g = ggk; b = gbk; out = goutk; }
    uint32_t v = *(const uint32_t*)(in + (size_t)row * 128 + lane * 2);
    float x0 = bf2f((u16)(v & 0xffff)), x1 = bf2f((u16)(v >> 16));
    float s = x0 + x1, q = x0 * x0 + x1 * x1;
#pragma unroll
    for (int mm = 1; mm < 64; mm <<= 1) { s += __shfl_xor(s, mm); q += __shfl_xor(q, mm); }
    float mean = s / 128.f, var = q / 128.f - mean * mean;
    float rstd = rsqrtf(var + 1e-5f);
    u16 o0 = f2bf((x0 - mean) * rstd * g[lane * 2] + b[lane * 2]);
    u16 o1 = f2bf((x1 - mean) * rstd * g[lane * 2 + 1] + b[lane * 2 + 1]);
    *(uint32_t*)(out + (size_t)row * 128 + lane * 2) = (uint32_t)o0 | ((uint32_t)o1 << 16);
  }
}

// ================= fused flash attention: static-offset softmax, bf16 Opart =================
// LDS trimmed to 32256 B -> 5 blocks/CU
__global__ __launch_bounds__(256, 5) void k_flash(const u16* __restrict__ Qa,
                                                  const u16* __restrict__ Ka,
                                                  const u16* __restrict__ VT,
                                                  const float* __restrict__ kk2,
                                                  u16* __restrict__ Opart,
                                                  float* __restrict__ lbuf) {
  const int h = blockIdx.y, qb = blockIdx.x, sp = blockIdx.z;
  const int tid = threadIdx.x, w = tid >> 6, lane = tid & 63;
  const int l16 = lane & 15, lh = lane >> 4;
  __shared__ u16 sK[64][100];
  __shared__ u16 sV[64][68];
  __shared__ u16 sP[4][16][68];
  __shared__ float sKK[512];

  ((float2*)sKK)[tid] = ((const float2*)(kk2 + sp * 512))[tid];

  const int qrow = qb * 64 + w * 16 + l16;
  bf8v qf[3];
#pragma unroll
  for (int c = 0; c < 3; ++c)
    qf[c] = *(const bf8v*)(Qa + (size_t)(h * NF + qrow) * DA + c * 32 + lh * 8);

  bf8v ONES;
#pragma unroll
  for (int i = 0; i < 8; ++i) ONES[i] = (short)0x3F80;

  const int crow = qb * 64 + w * 16 + (lh << 2);
  float l_run[4] = {0.f, 0.f, 0.f, 0.f};
  f4v accO[4];
#pragma unroll
  for (int d = 0; d < 4; ++d) accO[d] = (f4v){0.f, 0.f, 0.f, 0.f};

  const int kt0 = sp * 8;
  bf8v kreg[3], vreg[2];
  auto sload = [&](int t8) {
    int kb = (kt0 + t8) * 64;
#pragma unroll
    for (int i = 0; i < 3; ++i) {
      int c = tid + i * 256; int r = c / 12, off = (c % 12) * 8;
      kreg[i] = *(const bf8v*)(Ka + ((size_t)(h * NS) + kb + r) * DA + off);
    }
#pragma unroll
    for (int i = 0; i < 2; ++i) {
      int c = tid + i * 256; int d = c >> 3, off = (c & 7) * 8;
      vreg[i] = *(const bf8v*)(VT + ((size_t)(h * HD) + d) * NS + kb + off);
    }
  };
  auto swrite = [&]() {
#pragma unroll
    for (int i = 0; i < 3; ++i) {
      int c = tid + i * 256; int r = c / 12, off = (c % 12) * 8;
      *(bf8v*)&sK[r][off] = kreg[i];
    }
#pragma unroll
    for (int i = 0; i < 2; ++i) {
      int c = tid + i * 256; int d = c >> 3, off = (c & 7) * 8;
      *(bf8v*)&sV[d][off] = vreg[i];
    }
  };

  sload(0); swrite();
  __syncthreads();
  for (int t8 = 0; t8 < 8; ++t8) {
    if (t8 < 7) sload(t8 + 1);
#pragma unroll
    for (int j = 0; j < 4; ++j) {
      f4v s4 = (f4v){0.f, 0.f, 0.f, 0.f};
#pragma unroll
      for (int c = 0; c < 3; ++c) {
        bf8v kf = *(const bf8v*)&sK[j * 16 + l16][c * 32 + lh * 8];
        s4 = mfma16(qf[c], kf, s4);
      }
      float ck = sKK[t8 * 64 + j * 16 + l16];
#pragma unroll
      for (int r = 0; r < 4; ++r) {
        float pv = exp2f(s4[r] - ck);
        sP[w][(lh << 2) + r][j * 16 + l16] = f2bf(pv);
      }
    }
    bf8v pf0 = *(const bf8v*)&sP[w][l16][lh * 8];
    bf8v pf1 = *(const bf8v*)&sP[w][l16][32 + lh * 8];
    f4v ls = (f4v){0.f, 0.f, 0.f, 0.f};
    ls = mfma16(pf0, ONES, ls);
    ls = mfma16(pf1, ONES, ls);
#pragma unroll
    for (int r = 0; r < 4; ++r) l_run[r] += ls[r];
#pragma unroll
    for (int c = 0; c < 2; ++c) {
      bf8v pf = (c == 0) ? pf0 : pf1;
#pragma unroll
      for (int d = 0; d < 4; ++d) {
        bf8v vf = *(const bf8v*)&sV[d * 16 + l16][c * 32 + lh * 8];
        accO[d] = mfma16(pf, vf, accO[d]);
      }
    }
    __syncthreads();
    if (t8 < 7) swrite();
    __syncthreads();
  }
  size_t obase = (size_t)(sp * 8 + h) * NF + crow;
#pragma unroll
  for (int d = 0; d < 4; ++d)
#pragma unroll
    for (int r = 0; r < 4; ++r)
      Opart[(obase + r) * 64 + d * 16 + l16] = f2bf(accO[d][r]);
  if (l16 == 0) {
#pragma unroll
    for (int r = 0; r < 4; ++r) lbuf[obase + r] = l_run[r];
  }
}

// ================= combine the 2 NS-splits (bf16 partials) =================
__global__ void k_combine(const u16* __restrict__ Opart, const float* __restrict__ lbuf,
                          float* __restrict__ out) {
  int i4 = blockIdx.x * 256 + threadIdx.x;
  int n = i4 >> 7;
  int c4 = i4 & 127, h = c4 >> 4, d4 = c4 & 15;
  float l = lbuf[(size_t)h * NF + n] + lbuf[(size_t)(8 + h) * NF + n];
  float rl = 1.f / l;
  ushort4 a = ((const ushort4*)(Opart + ((size_t)h * NF + n) * 64))[d4];
  ushort4 b = ((const ushort4*)(Opart + ((size_t)(8 + h) * NF + n) * 64))[d4];
  float4 r;
  r.x = (bf2f(a.x) + bf2f(b.x)) * rl;
  r.y = (bf2f(a.y) + bf2f(b.y)) * rl;
  r.z = (bf2f(a.z) + bf2f(b.z)) * rl;
  r.w = (bf2f(a.w) + bf2f(b.w)) * rl;
  ((float4*)out)[i4] = r;
}

extern "C" void kernel_launch(void* const* d_in, const int* in_sizes, int n_in,
                              void* d_out, int out_size, void* d_ws, size_t ws_size,
                              hipStream_t stream) {
  (void)in_sizes; (void)n_in; (void)out_size; (void)ws_size;
  const float* front_feat = (const float*)d_in[0];
  const float* bev_xy     = (const float*)d_in[1];
  const float* sat_tokens = (const float*)d_in[2];
  const float* sat_xy     = (const float*)d_in[3];
  const float* plucker    = (const float*)d_in[4];
  const float* pos_w1 = (const float*)d_in[5];
  const float* pos_b1 = (const float*)d_in[6];
  const float* pos_w2 = (const float*)d_in[7];
  const float* pos_b2 = (const float*)d_in[8];
  const float* fa_w   = (const float*)d_in[9];
  const float* fa_b   = (const float*)d_in[10];
  const float* fa_ln_g = (const float*)d_in[11];
  const float* fa_ln_b = (const float*)d_in[12];
  const float* qn_g   = (const float*)d_in[13];
  const float* qn_b   = (const float*)d_in[14];
  const float* sa_w   = (const float*)d_in[15];
  const float* sa_b   = (const float*)d_in[16];
  const float* sa_ln_g = (const float*)d_in[17];
  const float* sa_ln_b = (const float*)d_in[18];
  const float* wq = (const float*)d_in[19];
  const float* bq = (const float*)d_in[20];
  const float* wk = (const float*)d_in[21];
  const float* bk = (const float*)d_in[22];
  const float* wv = (const float*)d_in[23];
  const float* bv = (const float*)d_in[24];
  const float* plk_w1 = (const float*)d_in[25];
  const float* plk_b1 = (const float*)d_in[26];
  const float* plk_w2 = (const float*)d_in[27];
  const float* plk_b2 = (const float*)d_in[28];
  const float* sxy_w1 = (const float*)d_in[29];
  const float* sxy_b1 = (const float*)d_in[30];
  const float* sxy_w2 = (const float*)d_in[31];
  const float* sxy_b2 = (const float*)d_in[32];
  const float* gqn_g = (const float*)d_in[33];
  const float* gqn_b = (const float*)d_in[34];
  const float* gkn_g = (const float*)d_in[35];
  const float* gkn_b = (const float*)d_in[36];
  const float* wqg = (const float*)d_in[37];
  const float* bqg = (const float*)d_in[38];
  const float* wkg = (const float*)d_in[39];
  const float* bkg = (const float*)d_in[40];

  char* ws = (char*)d_ws;
  size_t off = 0;
  auto alloc = [&](size_t bytes) {
    size_t r = off;
    off += (bytes + 255) & ~(size_t)255;
    return r;
  };
  u16*   wpool   = (u16*)(ws + alloc((size_t)TOTW * 2));
  float* bkv     = (float*)(ws + alloc(1024 * 4));
  u16*   ffT     = (u16*)(ws + alloc((size_t)NF * 320 * 2));
  u16*   pos_h   = (u16*)(ws + alloc((size_t)NF * MD * 2));
  u16*   plk_h   = (u16*)(ws + alloc((size_t)NF * GHID * 2));
  u16*   sxy_h   = (u16*)(ws + alloc((size_t)NS * GHID * 2));
  u16*   pos     = (u16*)(ws + alloc((size_t)NF * MD * 2));
  u16*   feat_pre= (u16*)(ws + alloc((size_t)NF * MD * 2));
  u16*   satf_pre= (u16*)(ws + alloc((size_t)NS * MD * 2));
  u16*   satf    = (u16*)(ws + alloc((size_t)NS * MD * 2));
  u16*   q_embed = (u16*)(ws + alloc((size_t)NF * MD * 2));
  u16*   plk2    = (u16*)(ws + alloc((size_t)NF * GHID * 2));
  u16*   sxy2    = (u16*)(ws + alloc((size_t)NS * GHID * 2));
  u16*   Qaug    = (u16*)(ws + alloc((size_t)8 * NF * DA * 2));
  u16*   Kaug    = (u16*)(ws + alloc((size_t)8 * NS * DA * 2));
  u16*   VT      = (u16*)(ws + alloc((size_t)8 * HD * NS * 2));
  float* kk2     = (float*)(ws + alloc((size_t)NS * 4));
  u16*   Opart   = (u16*)(ws + alloc((size_t)2 * 8 * NF * 64 * 2));
  float* lbuf    = (float*)(ws + alloc((size_t)2 * 8 * NF * 4));
  // aliases (producer dead before alias written)
  u16* plk_ln = plk_h;
  u16* sgf    = sxy_h;

  dim3 b256(256);
  // L0: convert + ffT + silus + aug pad/kk2
  k_l0<<<dim3(13953), b256, 0, stream>>>(
      pos_w2, fa_w, sa_w, wq, wk, wv, plk_w2, sxy_w2, wqg, wkg, sat_tokens,
      wpool, bk, bv, bkv, front_feat, ffT,
      bev_xy, pos_w1, pos_b1, pos_h,
      plucker, plk_w1, plk_b1, plk_h,
      sat_xy, sxy_w1, sxy_b1, sxy_h,
      Qaug, Kaug, kk2);

  // L1 GEMMs (128x64 tiles, plain epilogues)
  GP gpos {pos_h, wpool + OFF_POSW2, pos_b2, pos, 512, 512, 4096, EPI_OUT, 0.f, nullptr, nullptr, 0};
  GP gfeat{ffT, wpool + OFF_FAW, fa_b, feat_pre, 320, 512, 4096, EPI_OUT, 0.f, nullptr, nullptr, 0};
  GP gsat {wpool + OFF_SATT, wpool + OFF_SAW, sa_b, satf_pre, 768, 512, 1024, EPI_OUT, 0.f, nullptr, nullptr, 0};
  GP ggq1 {plk_h, wpool + OFF_PLKW2, plk_b2, plk2, 128, 128, 4096, EPI_OUT, 0.f, nullptr, nullptr, 0};
  GP ggk1 {sxy_h, wpool + OFF_SXYW2, sxy_b2, sxy2, 128, 128, 1024, EPI_OUT, 0.f, nullptr, nullptr, 0};
  k_gemm_L1<<<dim3(656), b256, 0, stream>>>(gpos, gfeat, gsat, ggq1, ggk1);

  // LNs
  k_ln_all<<<dim3(2560), b256, 0, stream>>>(
      feat_pre, pos, fa_ln_g, fa_ln_b, qn_g, qn_b, q_embed,
      satf_pre, sa_ln_g, sa_ln_b, satf,
      plk2, sxy2, gqn_g, gqn_b, gkn_g, gkn_b, plk_ln, sgf);

  // L2 GEMMs with fused rope/VT/geo epilogues (64x64 tiles)
  GP gq  {q_embed, wpool + OFF_WQ, bq, nullptr, 512, 512, 4096, EPI_ROPE, 0.125f * L2E, bev_xy, Qaug, NF};
  GP gkv {satf, wpool + OFF_WKV, bkv, nullptr, 512, 1024, 1024, EPI_ROPE, 1.f, sat_xy, Kaug, NS};
  GP ggq2{plk_ln, wpool + OFF_WQG, bqg, nullptr, 128, 128, 4096, EPI_GEO, 0.25f * L2E, nullptr, Qaug, NF};
  GP ggk2{sgf, wpool + OFF_WKG, bkg, nullptr, 128, 128, 1024, EPI_GEO, 1.f, nullptr, Kaug, NS};
  k_gemm_L2<<<dim3(928), b256, 0, stream>>>(gq, gkv, ggq2, ggk2, VT);

  k_flash<<<dim3(NF / 64, 8, 2), b256, 0, stream>>>(Qaug, Kaug, VT, kk2, Opart, lbuf);
  k_combine<<<dim3(NF * MD / 4 / 256), b256, 0, stream>>>(Opart, lbuf, (float*)d_out);
}